// Round 6
// baseline (161.631 us; speedup 1.0000x reference)
//
#include <hip/hip_runtime.h>
#include <stdint.h>

#define B_ 4
#define S_ 2048
#define D_ 768
#define U_ 768

typedef __bf16 bf16x8 __attribute__((ext_vector_type(8)));
typedef float f32x4 __attribute__((ext_vector_type(4)));

#define AS1 __attribute__((address_space(1)))
#define AS3 __attribute__((address_space(3)))

#define BAR() __builtin_amdgcn_s_barrier()
#define WAITV6() asm volatile("s_waitcnt vmcnt(6)" ::: "memory")
#define WAITV0() asm volatile("s_waitcnt vmcnt(0)" ::: "memory")
#define PRIO(x) __builtin_amdgcn_s_setprio(x)

__device__ __forceinline__ ushort f2bf(float f) {
    union { float f; uint32_t u; } v; v.f = f;
    uint32_t r = v.u + 0x7fffu + ((v.u >> 16) & 1u);
    return (ushort)(r >> 16);
}

__device__ __forceinline__ void gload_lds16(const void* gp, void* lp) {
    // width-16 global->LDS: HW scatters to (wave-uniform lds base) + lane*16
    __builtin_amdgcn_global_load_lds((AS1 void*)gp, (AS3 void*)lp, 16, 0, 0);
}

// ============================================================================
// 256x256 8-phase pipelined GEMM — the ONLY structure measured at full rate
// this session (scores: 16.5us = 6.16 TF/CU). BK=64, 8 waves 2Mx4N, counted
// vmcnt(6), XOR-swizzled LDS (conflicts measured 0), setprio around MFMA.
// C = A[M,K] @ Bt[N,K]^T.
// MODE 0: bf16 row-major out.  MODE 1: bf16 scattered to Vt[B][U][S]
// (ushort4-packed: acc i=0..3 are 4 consecutive s).  MODE 2: f32 * scale.
// LDS: sA[2][256*64] + sB[2][256*64] bf16 = 128 KiB dynamic.
// ============================================================================
template <int MODE>
__device__ __forceinline__ void gemm256(
    ushort* sm,
    const ushort* __restrict__ Ag, int lda,
    const ushort* __restrict__ Btg, int ldb,
    void* __restrict__ Cp, int ldc, int Kd, float scale,
    int ty, int tx)
{
    constexpr int ABUF = 256 * 64;
    ushort* sA = sm;
    ushort* sB = sm + 2 * ABUF;

    const int tid = threadIdx.x;
    const int l = tid & 63, w = tid >> 6;
    const int lr = l & 15, lg = l >> 4;
    const int wm = w >> 2, wn = w & 3;
    const int M0 = ty * 256, N0 = tx * 256;

    f32x4 acc[8][4];
#pragma unroll
    for (int m = 0; m < 8; ++m)
#pragma unroll
        for (int n = 0; n < 4; ++n)
            acc[m][n] = (f32x4){0.f, 0.f, 0.f, 0.f};

    const int NT = Kd >> 6;

    auto STA = [&](int buf, int qp, int kt) {
#pragma unroll
        for (int j = 0; j < 2; ++j) {
            int q = qp + j;
            int r0 = (w < 4) ? (q * 32 + w * 8) : (128 + q * 32 + (w - 4) * 8);
            int r = r0 + (l >> 3);
            int lc = ((l & 7) * 16) ^ ((r & 7) << 4);
            gload_lds16(Ag + (size_t)(M0 + r) * lda + kt * 64 + (lc >> 1),
                        sA + buf * ABUF + r0 * 64);
        }
    };
    auto STB = [&](int buf, int h, int kt) {
#pragma unroll
        for (int j = 0; j < 2; ++j) {
            int r0 = h * 128 + j * 64 + w * 8;
            int r = r0 + (l >> 3);
            int lc = ((l & 7) * 16) ^ ((r & 7) << 4);
            gload_lds16(Btg + (size_t)(N0 + r) * ldb + kt * 64 + (lc >> 1),
                        sB + buf * 16384 + r0 * 64);
        }
    };

    bf16x8 afr[2][2], bfr[4][2];
    auto LDB = [&](int buf) {
#pragma unroll
        for (int nf = 0; nf < 4; ++nf)
#pragma unroll
            for (int ks = 0; ks < 2; ++ks) {
                int r = wn * 64 + nf * 16 + lr;
                int off = r * 128 + ((ks * 64 + lg * 16) ^ ((r & 7) << 4));
                bfr[nf][ks] = *(const bf16x8*)((const char*)(sB + buf * 16384) + off);
            }
    };
    auto LDA = [&](int buf, int q) {
#pragma unroll
        for (int j = 0; j < 2; ++j)
#pragma unroll
            for (int ks = 0; ks < 2; ++ks) {
                int r = wm * 128 + (2 * q + j) * 16 + lr;
                int off = r * 128 + ((ks * 64 + lg * 16) ^ ((r & 7) << 4));
                afr[j][ks] = *(const bf16x8*)((const char*)(sA + buf * ABUF) + off);
            }
    };

#define MMQ(Q)                                                                 \
    PRIO(1);                                                                   \
    _Pragma("unroll")                                                          \
    for (int j = 0; j < 2; ++j)                                                \
        _Pragma("unroll")                                                      \
        for (int nf = 0; nf < 4; ++nf)                                         \
            _Pragma("unroll")                                                  \
            for (int ks = 0; ks < 2; ++ks)                                     \
                acc[2 * (Q) + j][nf] = __builtin_amdgcn_mfma_f32_16x16x32_bf16(\
                    afr[j][ks], bfr[nf][ks], acc[2 * (Q) + j][nf], 0, 0, 0);   \
    PRIO(0);

    STA(0, 0, 0); STA(0, 2, 0); STB(0, 0, 0); STB(0, 1, 0);
    if (NT > 1) {
        STB(1, 0, 1); STB(1, 1, 1); STA(1, 0, 1);
        WAITV6();
    } else {
        WAITV0();
    }
    BAR();

    for (int t = 0; t < NT; ++t) {
        const int c = t & 1;
        LDB(c); LDA(c, 0);
        if (t + 1 < NT) STA(c ^ 1, 2, t + 1);
        BAR();
        MMQ(0);
        BAR();
        LDA(c, 1);
        if (t + 2 < NT) STB(c, 0, t + 2);
        BAR();
        MMQ(1);
        BAR();
        LDA(c, 2);
        if (t + 2 < NT) STB(c, 1, t + 2);
        BAR();
        MMQ(2);
        BAR();
        LDA(c, 3);
        if (t + 2 < NT) STA(c, 0, t + 2);
        BAR();
        MMQ(3);
        if (t + 2 < NT) { WAITV6(); } else { WAITV0(); }
        BAR();
    }
#undef MMQ

    // epilogue: C/D frag mapping col = lane&15, row = (lane>>4)*4 + i
#pragma unroll
    for (int mf = 0; mf < 8; ++mf) {
#pragma unroll
        for (int nf = 0; nf < 4; ++nf) {
            if constexpr (MODE == 1) {
                // rows r0..r0+3 are 4 consecutive s at fixed column c
                int r0 = M0 + wm * 128 + mf * 16 + lg * 4;
                int c = N0 + wn * 64 + nf * 16 + lr;
                int b = r0 >> 11, s = r0 & 2047;
                ushort4 o;
                o.x = f2bf(acc[mf][nf][0]);
                o.y = f2bf(acc[mf][nf][1]);
                o.z = f2bf(acc[mf][nf][2]);
                o.w = f2bf(acc[mf][nf][3]);
                *(ushort4*)&((ushort*)Cp)[((size_t)b * U_ + c) * S_ + s] = o;
            } else {
#pragma unroll
                for (int i = 0; i < 4; ++i) {
                    int r = M0 + wm * 128 + mf * 16 + lg * 4 + i;
                    int c = N0 + wn * 64 + nf * 16 + lr;
                    float v = acc[mf][nf][i];
                    if constexpr (MODE == 0) {
                        ((ushort*)Cp)[(size_t)r * ldc + c] = f2bf(v);
                    } else {
                        ((float*)Cp)[(size_t)r * ldc + c] = v * scale;
                    }
                }
            }
        }
    }
}

// Q and K projections: 32 ty x {z,tx} in trios -> 192 blocks, exactly 1 round.
// Adjacent wg share the same xb A-panel (L2 reuse within an XCD).
__global__ __launch_bounds__(512) void proj_qk_kernel(
    const ushort* __restrict__ xb, const ushort* __restrict__ Wt,
    ushort* __restrict__ Qb, ushort* __restrict__ Kb) {
    extern __shared__ ushort sm[];
    const int b0 = blockIdx.x;                      // 192 = 8 XCD x 24
    const int wg = (b0 & 7) * 24 + (b0 >> 3);
    const int ty = wg / 6, rem = wg % 6;
    const int z = rem / 3, tx = rem % 3;
    gemm256<0>(sm, xb, D_, Wt + (size_t)z * U_ * D_, D_,
               z == 0 ? Qb : Kb, U_, D_, 1.f, ty, tx);
}

// V projection with transposed (Vt[B][U][S]) scatter epilogue — isolated so
// rocprof attributes its cost separately. 96 blocks.
__global__ __launch_bounds__(512) void proj_v_kernel(
    const ushort* __restrict__ xb, const ushort* __restrict__ Wt,
    ushort* __restrict__ Vt) {
    extern __shared__ ushort sm[];
    const int b0 = blockIdx.x;                      // 96 = 8 XCD x 12
    const int wg = (b0 & 7) * 12 + (b0 >> 3);
    const int ty = wg / 3, tx = wg % 3;
    gemm256<1>(sm, xb, D_, Wt + (size_t)2 * U_ * D_, D_,
               Vt, 0, D_, 1.f, ty, tx);
}

__global__ __launch_bounds__(512) void scores_kernel(
    const ushort* __restrict__ Qb, const ushort* __restrict__ Kb,
    float* __restrict__ Sc, float scale) {
    extern __shared__ ushort sm[];
    const int nwg = gridDim.x;                       // 256 or 64, %8==0
    const int b0 = blockIdx.x;
    const int wg = (b0 & 7) * (nwg >> 3) + (b0 >> 3);
    const int tx = wg & 7, ty = (wg >> 3) & 7, z = wg >> 6;
    gemm256<2>(sm, Qb + (size_t)z * S_ * U_, U_, Kb + (size_t)z * S_ * U_, U_,
               Sc + (size_t)z * S_ * S_, S_, U_, scale, ty, tx);
}

// PV at the proven 256x256 structure: 96 blocks (grid-quantization test).
// XCD-chunked so each XCD runs one batch's 12 blocks: V (3MB) fits its L2,
// and tx-trios sharing a P-panel are adjacent.
__global__ __launch_bounds__(512) void pv_kernel(
    const ushort* __restrict__ P, const ushort* __restrict__ Vt,
    float* __restrict__ out) {
    extern __shared__ ushort sm[];
    const int b0 = blockIdx.x;                      // 96 = 8 XCD x 12
    const int wg = (b0 & 7) * 12 + (b0 >> 3);
    const int z = wg / 24, rem = wg % 24;
    const int ty = rem / 3, tx = rem % 3;
    gemm256<2>(sm, P + (size_t)z * S_ * S_, S_, Vt + (size_t)z * U_ * S_, S_,
               out + (size_t)z * S_ * U_, U_, S_, 1.f, ty, tx);
}

// ======================= small helper kernels ========================

__global__ void cast_x_kernel(const float4* __restrict__ in,
                              ushort4* __restrict__ out, int n4) {
    int i = blockIdx.x * 256 + threadIdx.x;
    if (i >= n4) return;
    float4 v = in[i];
    ushort4 o;
    o.x = f2bf(v.x); o.y = f2bf(v.y); o.z = f2bf(v.z); o.w = f2bf(v.w);
    out[i] = o;
}

__global__ void transpose_w_kernel(const float* __restrict__ Wq,
                                   const float* __restrict__ Wk,
                                   const float* __restrict__ Wv,
                                   ushort* __restrict__ Wt) {
    const float* W = blockIdx.z == 0 ? Wq : (blockIdx.z == 1 ? Wk : Wv);
    __shared__ float t[32][33];
    int x0 = blockIdx.x * 32, y0 = blockIdx.y * 32;
    int tx = threadIdx.x;
    for (int i = threadIdx.y; i < 32; i += 8)
        t[i][tx] = W[(size_t)(y0 + i) * U_ + (x0 + tx)];
    __syncthreads();
    ushort* Wtz = Wt + (size_t)blockIdx.z * U_ * D_;
    for (int i = threadIdx.y; i < 32; i += 8)
        Wtz[(size_t)(x0 + i) * D_ + (y0 + tx)] = f2bf(t[tx][i]);
}

__global__ __launch_bounds__(256) void softmax_kernel(
    const float* __restrict__ Sc, ushort* __restrict__ P) {
    size_t row = (size_t)blockIdx.y * gridDim.x + blockIdx.x;
    const float4* r4 = (const float4*)(Sc + row * S_);
    int t = threadIdx.x;
    int w = t >> 6, l = t & 63;
    float4 a = r4[t], b = r4[t + 256];
    float mx = fmaxf(fmaxf(fmaxf(a.x, a.y), fmaxf(a.z, a.w)),
                     fmaxf(fmaxf(b.x, b.y), fmaxf(b.z, b.w)));
#pragma unroll
    for (int off = 32; off; off >>= 1) mx = fmaxf(mx, __shfl_xor(mx, off));
    __shared__ float red[8];
    if (l == 0) red[w] = mx;
    __syncthreads();
    mx = fmaxf(fmaxf(red[0], red[1]), fmaxf(red[2], red[3]));
    float e[8];
    e[0] = __expf(a.x - mx); e[1] = __expf(a.y - mx);
    e[2] = __expf(a.z - mx); e[3] = __expf(a.w - mx);
    e[4] = __expf(b.x - mx); e[5] = __expf(b.y - mx);
    e[6] = __expf(b.z - mx); e[7] = __expf(b.w - mx);
    float s = e[0] + e[1] + e[2] + e[3] + e[4] + e[5] + e[6] + e[7];
#pragma unroll
    for (int off = 32; off; off >>= 1) s += __shfl_xor(s, off);
    if (l == 0) red[4 + w] = s;
    __syncthreads();
    float inv = 1.f / (red[4] + red[5] + red[6] + red[7]);
    ushort4* p4 = (ushort4*)(P + row * S_);
    ushort4 o1, o2;
    o1.x = f2bf(e[0] * inv); o1.y = f2bf(e[1] * inv);
    o1.z = f2bf(e[2] * inv); o1.w = f2bf(e[3] * inv);
    o2.x = f2bf(e[4] * inv); o2.y = f2bf(e[5] * inv);
    o2.z = f2bf(e[6] * inv); o2.w = f2bf(e[7] * inv);
    p4[t] = o1; p4[t + 256] = o2;
}

extern "C" void kernel_launch(void* const* d_in, const int* in_sizes, int n_in,
                              void* d_out, int out_size, void* d_ws, size_t ws_size,
                              hipStream_t stream) {
    (void)in_sizes; (void)n_in; (void)out_size;
    const float* x = (const float*)d_in[0];
    const float* Wq = (const float*)d_in[1];
    const float* Wk = (const float*)d_in[2];
    const float* Wv = (const float*)d_in[3];
    float* out = (float*)d_out;

    char* ws = (char*)d_ws;
    size_t off = 0;
    auto alloc = [&](size_t bytes) -> void* {
        void* p = ws + off;
        off += (bytes + 255) & ~(size_t)255;
        return p;
    };
    ushort* xb = (ushort*)alloc((size_t)B_ * S_ * D_ * 2);
    ushort* Wt = (ushort*)alloc((size_t)3 * U_ * D_ * 2);
    ushort* Qb = (ushort*)alloc((size_t)B_ * S_ * U_ * 2);
    ushort* Kb = (ushort*)alloc((size_t)B_ * S_ * U_ * 2);
    ushort* Vt = (ushort*)alloc((size_t)B_ * S_ * U_ * 2);  // [B][U][S]
    ushort* P  = (ushort*)alloc((size_t)B_ * S_ * S_ * 2);
    bool full = (ws_size - off) >= (size_t)B_ * S_ * S_ * 4 + 256;
    float* Sc = (float*)alloc(full ? (size_t)B_ * S_ * S_ * 4 : (size_t)S_ * S_ * 4);

    hipFuncSetAttribute(reinterpret_cast<const void*>(proj_qk_kernel),
                        hipFuncAttributeMaxDynamicSharedMemorySize, 131072);
    hipFuncSetAttribute(reinterpret_cast<const void*>(proj_v_kernel),
                        hipFuncAttributeMaxDynamicSharedMemorySize, 131072);
    hipFuncSetAttribute(reinterpret_cast<const void*>(scores_kernel),
                        hipFuncAttributeMaxDynamicSharedMemorySize, 131072);
    hipFuncSetAttribute(reinterpret_cast<const void*>(pv_kernel),
                        hipFuncAttributeMaxDynamicSharedMemorySize, 131072);

    int n4 = B_ * S_ * D_ / 4;
    cast_x_kernel<<<(n4 + 255) / 256, 256, 0, stream>>>(
        (const float4*)x, (ushort4*)xb, n4);
    transpose_w_kernel<<<dim3(U_ / 32, D_ / 32, 3), dim3(32, 8), 0, stream>>>(
        Wq, Wk, Wv, Wt);
    proj_qk_kernel<<<192, 512, 131072, stream>>>(xb, Wt, Qb, Kb);
    proj_v_kernel<<<96, 512, 131072, stream>>>(xb, Wt, Vt);

    const float scale = 0.036084391824351615f;  // 1/sqrt(768)
    if (full) {
        scores_kernel<<<256, 512, 131072, stream>>>(Qb, Kb, Sc, scale);
        softmax_kernel<<<dim3(S_, B_), 256, 0, stream>>>(Sc, P);
    } else {
        for (int b = 0; b < B_; ++b) {
            scores_kernel<<<64, 512, 131072, stream>>>(
                Qb + (size_t)b * S_ * U_, Kb + (size_t)b * S_ * U_, Sc, scale);
            softmax_kernel<<<dim3(S_, 1), 256, 0, stream>>>(
                Sc, P + (size_t)b * S_ * S_);
        }
    }
    pv_kernel<<<96, 512, 131072, stream>>>(P, Vt, out);
}

// Round 7
// 155.190 us; speedup vs baseline: 1.0415x; 1.0415x over previous
//
#include <hip/hip_runtime.h>
#include <stdint.h>

#define B_ 4
#define S_ 2048
#define D_ 768
#define U_ 768

typedef __bf16 bf16x8 __attribute__((ext_vector_type(8)));
typedef float f32x4 __attribute__((ext_vector_type(4)));

#define AS1 __attribute__((address_space(1)))
#define AS3 __attribute__((address_space(3)))

#define BAR() __builtin_amdgcn_s_barrier()
#define WAITV6() asm volatile("s_waitcnt vmcnt(6)" ::: "memory")
#define WAITV0() asm volatile("s_waitcnt vmcnt(0)" ::: "memory")
#define PRIO(x) __builtin_amdgcn_s_setprio(x)

__device__ __forceinline__ ushort f2bf(float f) {
    union { float f; uint32_t u; } v; v.f = f;
    uint32_t r = v.u + 0x7fffu + ((v.u >> 16) & 1u);
    return (ushort)(r >> 16);
}

__device__ __forceinline__ void gload_lds16(const void* gp, void* lp) {
    // width-16 global->LDS: HW scatters to (wave-uniform lds base) + lane*16
    __builtin_amdgcn_global_load_lds((AS1 void*)gp, (AS3 void*)lp, 16, 0, 0);
}

// ============================================================================
// 256x256 8-phase pipelined GEMM (BK=64, 8 waves 2Mx4N, counted vmcnt(6),
// XOR-swizzled LDS — conflicts measured 0, setprio around MFMA).
// C = A[M,K] @ Bt[N,K]^T.
// MODE 0: bf16 row-major out.  MODE 1: bf16 scattered to Vt[B][U][S]
// (ushort4-packed).  MODE 2: f32 * scale.
// LDS: sA[2][256*64] + sB[2][256*64] bf16 = 128 KiB dynamic.
// ============================================================================
template <int MODE>
__device__ __forceinline__ void gemm256(
    ushort* sm,
    const ushort* __restrict__ Ag, int lda,
    const ushort* __restrict__ Btg, int ldb,
    void* __restrict__ Cp, int ldc, int Kd, float scale,
    int ty, int tx)
{
    constexpr int ABUF = 256 * 64;
    ushort* sA = sm;
    ushort* sB = sm + 2 * ABUF;

    const int tid = threadIdx.x;
    const int l = tid & 63, w = tid >> 6;
    const int lr = l & 15, lg = l >> 4;
    const int wm = w >> 2, wn = w & 3;
    const int M0 = ty * 256, N0 = tx * 256;

    f32x4 acc[8][4];
#pragma unroll
    for (int m = 0; m < 8; ++m)
#pragma unroll
        for (int n = 0; n < 4; ++n)
            acc[m][n] = (f32x4){0.f, 0.f, 0.f, 0.f};

    const int NT = Kd >> 6;

    auto STA = [&](int buf, int qp, int kt) {
#pragma unroll
        for (int j = 0; j < 2; ++j) {
            int q = qp + j;
            int r0 = (w < 4) ? (q * 32 + w * 8) : (128 + q * 32 + (w - 4) * 8);
            int r = r0 + (l >> 3);
            int lc = ((l & 7) * 16) ^ ((r & 7) << 4);
            gload_lds16(Ag + (size_t)(M0 + r) * lda + kt * 64 + (lc >> 1),
                        sA + buf * ABUF + r0 * 64);
        }
    };
    auto STB = [&](int buf, int h, int kt) {
#pragma unroll
        for (int j = 0; j < 2; ++j) {
            int r0 = h * 128 + j * 64 + w * 8;
            int r = r0 + (l >> 3);
            int lc = ((l & 7) * 16) ^ ((r & 7) << 4);
            gload_lds16(Btg + (size_t)(N0 + r) * ldb + kt * 64 + (lc >> 1),
                        sB + buf * 16384 + r0 * 64);
        }
    };

    bf16x8 afr[2][2], bfr[4][2];
    auto LDB = [&](int buf) {
#pragma unroll
        for (int nf = 0; nf < 4; ++nf)
#pragma unroll
            for (int ks = 0; ks < 2; ++ks) {
                int r = wn * 64 + nf * 16 + lr;
                int off = r * 128 + ((ks * 64 + lg * 16) ^ ((r & 7) << 4));
                bfr[nf][ks] = *(const bf16x8*)((const char*)(sB + buf * 16384) + off);
            }
    };
    auto LDA = [&](int buf, int q) {
#pragma unroll
        for (int j = 0; j < 2; ++j)
#pragma unroll
            for (int ks = 0; ks < 2; ++ks) {
                int r = wm * 128 + (2 * q + j) * 16 + lr;
                int off = r * 128 + ((ks * 64 + lg * 16) ^ ((r & 7) << 4));
                afr[j][ks] = *(const bf16x8*)((const char*)(sA + buf * ABUF) + off);
            }
    };

#define MMQ(Q)                                                                 \
    PRIO(1);                                                                   \
    _Pragma("unroll")                                                          \
    for (int j = 0; j < 2; ++j)                                                \
        _Pragma("unroll")                                                      \
        for (int nf = 0; nf < 4; ++nf)                                         \
            _Pragma("unroll")                                                  \
            for (int ks = 0; ks < 2; ++ks)                                     \
                acc[2 * (Q) + j][nf] = __builtin_amdgcn_mfma_f32_16x16x32_bf16(\
                    afr[j][ks], bfr[nf][ks], acc[2 * (Q) + j][nf], 0, 0, 0);   \
    PRIO(0);

    STA(0, 0, 0); STA(0, 2, 0); STB(0, 0, 0); STB(0, 1, 0);
    if (NT > 1) {
        STB(1, 0, 1); STB(1, 1, 1); STA(1, 0, 1);
        WAITV6();
    } else {
        WAITV0();
    }
    BAR();

    for (int t = 0; t < NT; ++t) {
        const int c = t & 1;
        LDB(c); LDA(c, 0);
        if (t + 1 < NT) STA(c ^ 1, 2, t + 1);
        BAR();
        MMQ(0);
        BAR();
        LDA(c, 1);
        if (t + 2 < NT) STB(c, 0, t + 2);
        BAR();
        MMQ(1);
        BAR();
        LDA(c, 2);
        if (t + 2 < NT) STB(c, 1, t + 2);
        BAR();
        MMQ(2);
        BAR();
        LDA(c, 3);
        if (t + 2 < NT) STA(c, 0, t + 2);
        BAR();
        MMQ(3);
        if (t + 2 < NT) { WAITV6(); } else { WAITV0(); }
        BAR();
    }
#undef MMQ

    // epilogue: C/D frag mapping col = lane&15, row = (lane>>4)*4 + i
#pragma unroll
    for (int mf = 0; mf < 8; ++mf) {
#pragma unroll
        for (int nf = 0; nf < 4; ++nf) {
            if constexpr (MODE == 1) {
                int r0 = M0 + wm * 128 + mf * 16 + lg * 4;
                int c = N0 + wn * 64 + nf * 16 + lr;
                int b = r0 >> 11, s = r0 & 2047;
                ushort4 o;
                o.x = f2bf(acc[mf][nf][0]);
                o.y = f2bf(acc[mf][nf][1]);
                o.z = f2bf(acc[mf][nf][2]);
                o.w = f2bf(acc[mf][nf][3]);
                *(ushort4*)&((ushort*)Cp)[((size_t)b * U_ + c) * S_ + s] = o;
            } else {
#pragma unroll
                for (int i = 0; i < 4; ++i) {
                    int r = M0 + wm * 128 + mf * 16 + lg * 4 + i;
                    int c = N0 + wn * 64 + nf * 16 + lr;
                    float v = acc[mf][nf][i];
                    if constexpr (MODE == 0) {
                        ((ushort*)Cp)[(size_t)r * ldc + c] = f2bf(v);
                    } else {
                        ((float*)Cp)[(size_t)r * ldc + c] = v * scale;
                    }
                }
            }
        }
    }
}

// Q and K projections: 192 blocks, exactly 1 round.
__global__ __launch_bounds__(512) void proj_qk_kernel(
    const ushort* __restrict__ xb, const ushort* __restrict__ Wt,
    ushort* __restrict__ Qb, ushort* __restrict__ Kb) {
    extern __shared__ ushort sm[];
    const int b0 = blockIdx.x;                      // 192 = 8 XCD x 24
    const int wg = (b0 & 7) * 24 + (b0 >> 3);
    const int ty = wg / 6, rem = wg % 6;
    const int z = rem / 3, tx = rem % 3;
    gemm256<0>(sm, xb, D_, Wt + (size_t)z * U_ * D_, D_,
               z == 0 ? Qb : Kb, U_, D_, 1.f, ty, tx);
}

// V projection with transposed (Vt[B][U][S]) scatter epilogue. 96 blocks.
__global__ __launch_bounds__(512) void proj_v_kernel(
    const ushort* __restrict__ xb, const ushort* __restrict__ Wt,
    ushort* __restrict__ Vt) {
    extern __shared__ ushort sm[];
    const int b0 = blockIdx.x;                      // 96 = 8 XCD x 12
    const int wg = (b0 & 7) * 12 + (b0 >> 3);
    const int ty = wg / 3, tx = wg % 3;
    gemm256<1>(sm, xb, D_, Wt + (size_t)2 * U_ * D_, D_,
               Vt, 0, D_, 1.f, ty, tx);
}

__global__ __launch_bounds__(512) void scores_kernel(
    const ushort* __restrict__ Qb, const ushort* __restrict__ Kb,
    float* __restrict__ Sc, float scale) {
    extern __shared__ ushort sm[];
    const int nwg = gridDim.x;                       // 256 or 64, %8==0
    const int b0 = blockIdx.x;
    const int wg = (b0 & 7) * (nwg >> 3) + (b0 >> 3);
    const int tx = wg & 7, ty = (wg >> 3) & 7, z = wg >> 6;
    gemm256<2>(sm, Qb + (size_t)z * S_ * U_, U_, Kb + (size_t)z * S_ * U_, U_,
               Sc + (size_t)z * S_ * S_, S_, U_, scale, ty, tx);
}

// ============================================================================
// PV with split-K=2: 192 blocks (one full round). Block (z,kc,ty,tx) computes
// K in [kc*1024, +1024) of output tile (ty,tx) of batch z, at the proven 256²
// structure. kc=0 -> p0 (= out), kc=1 -> p1 (= dead Sc region, reused).
// XCD-chunked: each XCD owns one (z,kc): V-half panels (1.5 MB) L2-resident.
// ============================================================================
__global__ __launch_bounds__(512) void pv_split_kernel(
    const ushort* __restrict__ P, const ushort* __restrict__ Vt,
    float* __restrict__ p0, float* __restrict__ p1) {
    extern __shared__ ushort sm[];
    const int b0 = blockIdx.x;                      // 192 = 8 XCD x 24
    const int wg = (b0 & 7) * 24 + (b0 >> 3);
    const int zk = wg / 24, rem = wg % 24;
    const int z = zk >> 1, kc = zk & 1;
    const int ty = rem / 3, tx = rem % 3;
    float* dst = (kc ? p1 : p0) + (size_t)z * S_ * U_;
    gemm256<2>(sm, P + (size_t)z * S_ * S_ + kc * 1024, S_,
               Vt + (size_t)z * U_ * S_ + kc * 1024, S_,
               dst, U_, 1024, 1.f, ty, tx);
}

// out[i] += p1[i]  (split-K combine; 75.6 MB traffic, HBM-bound)
__global__ void reduce_add_kernel(float4* __restrict__ out,
                                  const float4* __restrict__ p1, int n4) {
    int i = blockIdx.x * 256 + threadIdx.x;
    const int stride = gridDim.x * 256;
    for (; i < n4; i += stride) {
        float4 a = out[i], b = p1[i];
        a.x += b.x; a.y += b.y; a.z += b.z; a.w += b.w;
        out[i] = a;
    }
}

// PV without split (fallback when ws lacks the full Sc region). 96 blocks.
__global__ __launch_bounds__(512) void pv_kernel(
    const ushort* __restrict__ P, const ushort* __restrict__ Vt,
    float* __restrict__ out) {
    extern __shared__ ushort sm[];
    const int b0 = blockIdx.x;                      // 96 = 8 XCD x 12
    const int wg = (b0 & 7) * 12 + (b0 >> 3);
    const int z = wg / 24, rem = wg % 24;
    const int ty = rem / 3, tx = rem % 3;
    gemm256<2>(sm, P + (size_t)z * S_ * S_, S_, Vt + (size_t)z * U_ * S_, S_,
               out + (size_t)z * S_ * U_, U_, S_, 1.f, ty, tx);
}

// ======================= small helper kernels ========================

__global__ void cast_x_kernel(const float4* __restrict__ in,
                              ushort4* __restrict__ out, int n4) {
    int i = blockIdx.x * 256 + threadIdx.x;
    if (i >= n4) return;
    float4 v = in[i];
    ushort4 o;
    o.x = f2bf(v.x); o.y = f2bf(v.y); o.z = f2bf(v.z); o.w = f2bf(v.w);
    out[i] = o;
}

__global__ void transpose_w_kernel(const float* __restrict__ Wq,
                                   const float* __restrict__ Wk,
                                   const float* __restrict__ Wv,
                                   ushort* __restrict__ Wt) {
    const float* W = blockIdx.z == 0 ? Wq : (blockIdx.z == 1 ? Wk : Wv);
    __shared__ float t[32][33];
    int x0 = blockIdx.x * 32, y0 = blockIdx.y * 32;
    int tx = threadIdx.x;
    for (int i = threadIdx.y; i < 32; i += 8)
        t[i][tx] = W[(size_t)(y0 + i) * U_ + (x0 + tx)];
    __syncthreads();
    ushort* Wtz = Wt + (size_t)blockIdx.z * U_ * D_;
    for (int i = threadIdx.y; i < 32; i += 8)
        Wtz[(size_t)(x0 + i) * D_ + (y0 + tx)] = f2bf(t[tx][i]);
}

__global__ __launch_bounds__(256) void softmax_kernel(
    const float* __restrict__ Sc, ushort* __restrict__ P) {
    size_t row = (size_t)blockIdx.y * gridDim.x + blockIdx.x;
    const float4* r4 = (const float4*)(Sc + row * S_);
    int t = threadIdx.x;
    int w = t >> 6, l = t & 63;
    float4 a = r4[t], b = r4[t + 256];
    float mx = fmaxf(fmaxf(fmaxf(a.x, a.y), fmaxf(a.z, a.w)),
                     fmaxf(fmaxf(b.x, b.y), fmaxf(b.z, b.w)));
#pragma unroll
    for (int off = 32; off; off >>= 1) mx = fmaxf(mx, __shfl_xor(mx, off));
    __shared__ float red[8];
    if (l == 0) red[w] = mx;
    __syncthreads();
    mx = fmaxf(fmaxf(red[0], red[1]), fmaxf(red[2], red[3]));
    float e[8];
    e[0] = __expf(a.x - mx); e[1] = __expf(a.y - mx);
    e[2] = __expf(a.z - mx); e[3] = __expf(a.w - mx);
    e[4] = __expf(b.x - mx); e[5] = __expf(b.y - mx);
    e[6] = __expf(b.z - mx); e[7] = __expf(b.w - mx);
    float s = e[0] + e[1] + e[2] + e[3] + e[4] + e[5] + e[6] + e[7];
#pragma unroll
    for (int off = 32; off; off >>= 1) s += __shfl_xor(s, off);
    if (l == 0) red[4 + w] = s;
    __syncthreads();
    float inv = 1.f / (red[4] + red[5] + red[6] + red[7]);
    ushort4* p4 = (ushort4*)(P + row * S_);
    ushort4 o1, o2;
    o1.x = f2bf(e[0] * inv); o1.y = f2bf(e[1] * inv);
    o1.z = f2bf(e[2] * inv); o1.w = f2bf(e[3] * inv);
    o2.x = f2bf(e[4] * inv); o2.y = f2bf(e[5] * inv);
    o2.z = f2bf(e[6] * inv); o2.w = f2bf(e[7] * inv);
    p4[t] = o1; p4[t + 256] = o2;
}

extern "C" void kernel_launch(void* const* d_in, const int* in_sizes, int n_in,
                              void* d_out, int out_size, void* d_ws, size_t ws_size,
                              hipStream_t stream) {
    (void)in_sizes; (void)n_in; (void)out_size;
    const float* x = (const float*)d_in[0];
    const float* Wq = (const float*)d_in[1];
    const float* Wk = (const float*)d_in[2];
    const float* Wv = (const float*)d_in[3];
    float* out = (float*)d_out;

    char* ws = (char*)d_ws;
    size_t off = 0;
    auto alloc = [&](size_t bytes) -> void* {
        void* p = ws + off;
        off += (bytes + 255) & ~(size_t)255;
        return p;
    };
    ushort* xb = (ushort*)alloc((size_t)B_ * S_ * D_ * 2);
    ushort* Wt = (ushort*)alloc((size_t)3 * U_ * D_ * 2);
    ushort* Qb = (ushort*)alloc((size_t)B_ * S_ * U_ * 2);
    ushort* Kb = (ushort*)alloc((size_t)B_ * S_ * U_ * 2);
    ushort* Vt = (ushort*)alloc((size_t)B_ * S_ * U_ * 2);  // [B][U][S]
    ushort* P  = (ushort*)alloc((size_t)B_ * S_ * S_ * 2);
    bool full = (ws_size - off) >= (size_t)B_ * S_ * S_ * 4 + 256;
    float* Sc = (float*)alloc(full ? (size_t)B_ * S_ * S_ * 4 : (size_t)S_ * S_ * 4);

    hipFuncSetAttribute(reinterpret_cast<const void*>(proj_qk_kernel),
                        hipFuncAttributeMaxDynamicSharedMemorySize, 131072);
    hipFuncSetAttribute(reinterpret_cast<const void*>(proj_v_kernel),
                        hipFuncAttributeMaxDynamicSharedMemorySize, 131072);
    hipFuncSetAttribute(reinterpret_cast<const void*>(scores_kernel),
                        hipFuncAttributeMaxDynamicSharedMemorySize, 131072);
    hipFuncSetAttribute(reinterpret_cast<const void*>(pv_split_kernel),
                        hipFuncAttributeMaxDynamicSharedMemorySize, 131072);
    hipFuncSetAttribute(reinterpret_cast<const void*>(pv_kernel),
                        hipFuncAttributeMaxDynamicSharedMemorySize, 131072);

    int n4 = B_ * S_ * D_ / 4;
    cast_x_kernel<<<(n4 + 255) / 256, 256, 0, stream>>>(
        (const float4*)x, (ushort4*)xb, n4);
    transpose_w_kernel<<<dim3(U_ / 32, D_ / 32, 3), dim3(32, 8), 0, stream>>>(
        Wq, Wk, Wv, Wt);
    proj_qk_kernel<<<192, 512, 131072, stream>>>(xb, Wt, Qb, Kb);
    proj_v_kernel<<<96, 512, 131072, stream>>>(xb, Wt, Vt);

    const float scale = 0.036084391824351615f;  // 1/sqrt(768)
    if (full) {
        scores_kernel<<<256, 512, 131072, stream>>>(Qb, Kb, Sc, scale);
        softmax_kernel<<<dim3(S_, B_), 256, 0, stream>>>(Sc, P);
        // Sc is dead after softmax: reuse its first 25.2 MB for the kc=1
        // split-K partial.
        float* p1 = Sc;
        pv_split_kernel<<<192, 512, 131072, stream>>>(P, Vt, out, p1);
        reduce_add_kernel<<<2048, 256, 0, stream>>>(
            (float4*)out, (const float4*)p1, B_ * S_ * U_ / 4);
    } else {
        for (int b = 0; b < B_; ++b) {
            scores_kernel<<<64, 512, 131072, stream>>>(
                Qb + (size_t)b * S_ * U_, Kb + (size_t)b * S_ * U_, Sc, scale);
            softmax_kernel<<<dim3(S_, 1), 256, 0, stream>>>(
                Sc, P + (size_t)b * S_ * S_);
        }
        pv_kernel<<<96, 512, 131072, stream>>>(P, Vt, out);
    }
}

// Round 8
// 145.477 us; speedup vs baseline: 1.1110x; 1.0668x over previous
//
#include <hip/hip_runtime.h>
#include <stdint.h>

#define B_ 4
#define S_ 2048
#define D_ 768
#define U_ 768

typedef __bf16 bf16x8 __attribute__((ext_vector_type(8)));
typedef float f32x4 __attribute__((ext_vector_type(4)));

#define AS1 __attribute__((address_space(1)))
#define AS3 __attribute__((address_space(3)))

#define BAR() __builtin_amdgcn_s_barrier()
#define WAITV6() asm volatile("s_waitcnt vmcnt(6)" ::: "memory")
#define WAITV0() asm volatile("s_waitcnt vmcnt(0)" ::: "memory")
#define PRIO(x) __builtin_amdgcn_s_setprio(x)

__device__ __forceinline__ ushort f2bf(float f) {
    union { float f; uint32_t u; } v; v.f = f;
    uint32_t r = v.u + 0x7fffu + ((v.u >> 16) & 1u);
    return (ushort)(r >> 16);
}

__device__ __forceinline__ float bflo(uint32_t u) {
    union { uint32_t u; float f; } v; v.u = u << 16; return v.f;
}
__device__ __forceinline__ float bfhi(uint32_t u) {
    union { uint32_t u; float f; } v; v.u = u & 0xffff0000u; return v.f;
}

__device__ __forceinline__ void gload_lds16(const void* gp, void* lp) {
    // width-16 global->LDS: HW scatters to (wave-uniform lds base) + lane*16
    __builtin_amdgcn_global_load_lds((AS1 void*)gp, (AS3 void*)lp, 16, 0, 0);
}

// ============================================================================
// 256x256 8-phase pipelined GEMM (BK=64, 8 waves 2Mx4N, counted vmcnt(6),
// XOR-swizzled LDS — conflicts measured 0, setprio around MFMA).
// C = A[M,K] @ Bt[N,K]^T.
// MODE 0: bf16 row-major out, value*scale.  MODE 1: bf16 scattered to
// Vt[B][U][S] (ushort4-packed).  MODE 2: f32 * scale.
// LDS: sA[2][256*64] + sB[2][256*64] bf16 = 128 KiB dynamic.
// ============================================================================
template <int MODE>
__device__ __forceinline__ void gemm256(
    ushort* sm,
    const ushort* __restrict__ Ag, int lda,
    const ushort* __restrict__ Btg, int ldb,
    void* __restrict__ Cp, int ldc, int Kd, float scale,
    int ty, int tx)
{
    constexpr int ABUF = 256 * 64;
    ushort* sA = sm;
    ushort* sB = sm + 2 * ABUF;

    const int tid = threadIdx.x;
    const int l = tid & 63, w = tid >> 6;
    const int lr = l & 15, lg = l >> 4;
    const int wm = w >> 2, wn = w & 3;
    const int M0 = ty * 256, N0 = tx * 256;

    f32x4 acc[8][4];
#pragma unroll
    for (int m = 0; m < 8; ++m)
#pragma unroll
        for (int n = 0; n < 4; ++n)
            acc[m][n] = (f32x4){0.f, 0.f, 0.f, 0.f};

    const int NT = Kd >> 6;

    auto STA = [&](int buf, int qp, int kt) {
#pragma unroll
        for (int j = 0; j < 2; ++j) {
            int q = qp + j;
            int r0 = (w < 4) ? (q * 32 + w * 8) : (128 + q * 32 + (w - 4) * 8);
            int r = r0 + (l >> 3);
            int lc = ((l & 7) * 16) ^ ((r & 7) << 4);
            gload_lds16(Ag + (size_t)(M0 + r) * lda + kt * 64 + (lc >> 1),
                        sA + buf * ABUF + r0 * 64);
        }
    };
    auto STB = [&](int buf, int h, int kt) {
#pragma unroll
        for (int j = 0; j < 2; ++j) {
            int r0 = h * 128 + j * 64 + w * 8;
            int r = r0 + (l >> 3);
            int lc = ((l & 7) * 16) ^ ((r & 7) << 4);
            gload_lds16(Btg + (size_t)(N0 + r) * ldb + kt * 64 + (lc >> 1),
                        sB + buf * 16384 + r0 * 64);
        }
    };

    bf16x8 afr[2][2], bfr[4][2];
    auto LDB = [&](int buf) {
#pragma unroll
        for (int nf = 0; nf < 4; ++nf)
#pragma unroll
            for (int ks = 0; ks < 2; ++ks) {
                int r = wn * 64 + nf * 16 + lr;
                int off = r * 128 + ((ks * 64 + lg * 16) ^ ((r & 7) << 4));
                bfr[nf][ks] = *(const bf16x8*)((const char*)(sB + buf * 16384) + off);
            }
    };
    auto LDA = [&](int buf, int q) {
#pragma unroll
        for (int j = 0; j < 2; ++j)
#pragma unroll
            for (int ks = 0; ks < 2; ++ks) {
                int r = wm * 128 + (2 * q + j) * 16 + lr;
                int off = r * 128 + ((ks * 64 + lg * 16) ^ ((r & 7) << 4));
                afr[j][ks] = *(const bf16x8*)((const char*)(sA + buf * ABUF) + off);
            }
    };

#define MMQ(Q)                                                                 \
    PRIO(1);                                                                   \
    _Pragma("unroll")                                                          \
    for (int j = 0; j < 2; ++j)                                                \
        _Pragma("unroll")                                                      \
        for (int nf = 0; nf < 4; ++nf)                                         \
            _Pragma("unroll")                                                  \
            for (int ks = 0; ks < 2; ++ks)                                     \
                acc[2 * (Q) + j][nf] = __builtin_amdgcn_mfma_f32_16x16x32_bf16(\
                    afr[j][ks], bfr[nf][ks], acc[2 * (Q) + j][nf], 0, 0, 0);   \
    PRIO(0);

    STA(0, 0, 0); STA(0, 2, 0); STB(0, 0, 0); STB(0, 1, 0);
    if (NT > 1) {
        STB(1, 0, 1); STB(1, 1, 1); STA(1, 0, 1);
        WAITV6();
    } else {
        WAITV0();
    }
    BAR();

    for (int t = 0; t < NT; ++t) {
        const int c = t & 1;
        LDB(c); LDA(c, 0);
        if (t + 1 < NT) STA(c ^ 1, 2, t + 1);
        BAR();
        MMQ(0);
        BAR();
        LDA(c, 1);
        if (t + 2 < NT) STB(c, 0, t + 2);
        BAR();
        MMQ(1);
        BAR();
        LDA(c, 2);
        if (t + 2 < NT) STB(c, 1, t + 2);
        BAR();
        MMQ(2);
        BAR();
        LDA(c, 3);
        if (t + 2 < NT) STA(c, 0, t + 2);
        BAR();
        MMQ(3);
        if (t + 2 < NT) { WAITV6(); } else { WAITV0(); }
        BAR();
    }
#undef MMQ

    // epilogue: C/D frag mapping col = lane&15, row = (lane>>4)*4 + i
#pragma unroll
    for (int mf = 0; mf < 8; ++mf) {
#pragma unroll
        for (int nf = 0; nf < 4; ++nf) {
            if constexpr (MODE == 1) {
                int r0 = M0 + wm * 128 + mf * 16 + lg * 4;
                int c = N0 + wn * 64 + nf * 16 + lr;
                int b = r0 >> 11, s = r0 & 2047;
                ushort4 o;
                o.x = f2bf(acc[mf][nf][0]);
                o.y = f2bf(acc[mf][nf][1]);
                o.z = f2bf(acc[mf][nf][2]);
                o.w = f2bf(acc[mf][nf][3]);
                *(ushort4*)&((ushort*)Cp)[((size_t)b * U_ + c) * S_ + s] = o;
            } else {
#pragma unroll
                for (int i = 0; i < 4; ++i) {
                    int r = M0 + wm * 128 + mf * 16 + lg * 4 + i;
                    int c = N0 + wn * 64 + nf * 16 + lr;
                    float v = acc[mf][nf][i];
                    if constexpr (MODE == 0) {
                        ((ushort*)Cp)[(size_t)r * ldc + c] = f2bf(v * scale);
                    } else {
                        ((float*)Cp)[(size_t)r * ldc + c] = v * scale;
                    }
                }
            }
        }
    }
}

// ============================================================================
// Merged QKV projection: 288 blocks (one kernel, clean rocprof attribution).
// wg -> (ty, z, tx) with trios sharing an A-panel XCD-adjacent. Q gets the
// softmax scale folded into its epilogue (scores can then emit bf16 raw).
// ============================================================================
__global__ __launch_bounds__(512) void proj_kernel(
    const ushort* __restrict__ xb, const ushort* __restrict__ Wt,
    ushort* __restrict__ Qb, ushort* __restrict__ Kb,
    ushort* __restrict__ Vt, float qscale) {
    extern __shared__ ushort sm[];
    const int b0 = blockIdx.x;                      // 288 = 8 XCD x 36
    const int wg = (b0 & 7) * 36 + (b0 >> 3);
    const int ty = wg / 9, rem = wg % 9;
    const int z = rem / 3, tx = rem % 3;
    if (z == 0)
        gemm256<0>(sm, xb, D_, Wt, D_, Qb, U_, D_, qscale, ty, tx);
    else if (z == 1)
        gemm256<0>(sm, xb, D_, Wt + (size_t)U_ * D_, D_, Kb, U_, D_, 1.f, ty, tx);
    else
        gemm256<1>(sm, xb, D_, Wt + (size_t)2 * U_ * D_, D_, Vt, 0, D_, 1.f, ty, tx);
}

// scores -> bf16 (scale already folded into Q). 256 blocks.
__global__ __launch_bounds__(512) void scores_kernel(
    const ushort* __restrict__ Qb, const ushort* __restrict__ Kb,
    ushort* __restrict__ Sc) {
    extern __shared__ ushort sm[];
    const int nwg = gridDim.x;                       // 256 or 64, %8==0
    const int b0 = blockIdx.x;
    const int wg = (b0 & 7) * (nwg >> 3) + (b0 >> 3);
    const int tx = wg & 7, ty = (wg >> 3) & 7, z = wg >> 6;
    gemm256<0>(sm, Qb + (size_t)z * S_ * U_, U_, Kb + (size_t)z * S_ * U_, U_,
               Sc + (size_t)z * S_ * S_, S_, U_, 1.f, ty, tx);
}

// PV split-K=2: 192 blocks, proven 256² structure, kc=1 -> p1 (reused Sc mem).
__global__ __launch_bounds__(512) void pv_split_kernel(
    const ushort* __restrict__ P, const ushort* __restrict__ Vt,
    float* __restrict__ p0, float* __restrict__ p1) {
    extern __shared__ ushort sm[];
    const int b0 = blockIdx.x;                      // 192 = 8 XCD x 24
    const int wg = (b0 & 7) * 24 + (b0 >> 3);
    const int zk = wg / 24, rem = wg % 24;
    const int z = zk >> 1, kc = zk & 1;
    const int ty = rem / 3, tx = rem % 3;
    float* dst = (kc ? p1 : p0) + (size_t)z * S_ * U_;
    gemm256<2>(sm, P + (size_t)z * S_ * S_ + kc * 1024, S_,
               Vt + (size_t)z * U_ * S_ + kc * 1024, S_,
               dst, U_, 1024, 1.f, ty, tx);
}

// out[i] += p1[i]  (split-K combine; 75.6 MB traffic, HBM-bound)
__global__ void reduce_add_kernel(float4* __restrict__ out,
                                  const float4* __restrict__ p1, int n4) {
    int i = blockIdx.x * 256 + threadIdx.x;
    const int stride = gridDim.x * 256;
    for (; i < n4; i += stride) {
        float4 a = out[i], b = p1[i];
        a.x += b.x; a.y += b.y; a.z += b.z; a.w += b.w;
        out[i] = a;
    }
}

// PV without split (fallback when ws lacks the full Sc region). 96 blocks.
__global__ __launch_bounds__(512) void pv_kernel(
    const ushort* __restrict__ P, const ushort* __restrict__ Vt,
    float* __restrict__ out) {
    extern __shared__ ushort sm[];
    const int b0 = blockIdx.x;                      // 96 = 8 XCD x 12
    const int wg = (b0 & 7) * 12 + (b0 >> 3);
    const int z = wg / 24, rem = wg % 24;
    const int ty = rem / 3, tx = rem % 3;
    gemm256<2>(sm, P + (size_t)z * S_ * S_, S_, Vt + (size_t)z * U_ * S_, S_,
               out + (size_t)z * S_ * U_, U_, S_, 1.f, ty, tx);
}

// ======================= small helper kernels ========================

// Merged input prep: blocks [0,6144) cast x -> bf16; blocks [6144,7872)
// transpose W{q,k,v} -> Wt bf16 [z][U][D]. Branch is block-uniform.
__global__ __launch_bounds__(256) void prep_kernel(
    const float* __restrict__ x,
    const float* __restrict__ Wq, const float* __restrict__ Wk,
    const float* __restrict__ Wv,
    ushort* __restrict__ xb, ushort* __restrict__ Wt) {
    __shared__ float tsh[32][33];
    const int bid = blockIdx.x, tid = threadIdx.x;
    if (bid < 6144) {
        int i = bid * 256 + tid;                    // n4 = 6144*256 exactly
        float4 v = ((const float4*)x)[i];
        ushort4 o;
        o.x = f2bf(v.x); o.y = f2bf(v.y); o.z = f2bf(v.z); o.w = f2bf(v.w);
        ((ushort4*)xb)[i] = o;
    } else {
        int b2 = bid - 6144;
        int zz = b2 / 576, rem = b2 % 576;
        int by = rem / 24, bx = rem % 24;
        const float* W = zz == 0 ? Wq : (zz == 1 ? Wk : Wv);
        int x0 = bx * 32, y0 = by * 32;
        int txx = tid & 31, tyy = tid >> 5;         // 32 x 8
        for (int i = tyy; i < 32; i += 8)
            tsh[i][txx] = W[(size_t)(y0 + i) * U_ + (x0 + txx)];
        __syncthreads();
        ushort* Wtz = Wt + (size_t)zz * U_ * D_;
        for (int i = tyy; i < 32; i += 8)
            Wtz[(size_t)(x0 + i) * D_ + (y0 + txx)] = f2bf(tsh[txx][i]);
    }
}

// Row softmax over bf16 scores -> bf16 P. One row per block; each thread
// owns 8 contiguous cols (one 16B load + one 16B store).
__global__ __launch_bounds__(256) void softmax_kernel(
    const ushort* __restrict__ Sc, ushort* __restrict__ P) {
    size_t row = (size_t)blockIdx.y * gridDim.x + blockIdx.x;
    const uint4* r4 = (const uint4*)(Sc + row * S_);
    int t = threadIdx.x;
    int w = t >> 6, l = t & 63;
    uint4 a = r4[t];
    float e[8];
    e[0] = bflo(a.x); e[1] = bfhi(a.x);
    e[2] = bflo(a.y); e[3] = bfhi(a.y);
    e[4] = bflo(a.z); e[5] = bfhi(a.z);
    e[6] = bflo(a.w); e[7] = bfhi(a.w);
    float mx = fmaxf(fmaxf(fmaxf(e[0], e[1]), fmaxf(e[2], e[3])),
                     fmaxf(fmaxf(e[4], e[5]), fmaxf(e[6], e[7])));
#pragma unroll
    for (int off = 32; off; off >>= 1) mx = fmaxf(mx, __shfl_xor(mx, off));
    __shared__ float red[8];
    if (l == 0) red[w] = mx;
    __syncthreads();
    mx = fmaxf(fmaxf(red[0], red[1]), fmaxf(red[2], red[3]));
    float s = 0.f;
#pragma unroll
    for (int i = 0; i < 8; ++i) { e[i] = __expf(e[i] - mx); s += e[i]; }
#pragma unroll
    for (int off = 32; off; off >>= 1) s += __shfl_xor(s, off);
    if (l == 0) red[4 + w] = s;
    __syncthreads();
    float inv = 1.f / (red[4] + red[5] + red[6] + red[7]);
    uint4 o;
    o.x = (uint32_t)f2bf(e[0] * inv) | ((uint32_t)f2bf(e[1] * inv) << 16);
    o.y = (uint32_t)f2bf(e[2] * inv) | ((uint32_t)f2bf(e[3] * inv) << 16);
    o.z = (uint32_t)f2bf(e[4] * inv) | ((uint32_t)f2bf(e[5] * inv) << 16);
    o.w = (uint32_t)f2bf(e[6] * inv) | ((uint32_t)f2bf(e[7] * inv) << 16);
    ((uint4*)(P + row * S_))[t] = o;
}

extern "C" void kernel_launch(void* const* d_in, const int* in_sizes, int n_in,
                              void* d_out, int out_size, void* d_ws, size_t ws_size,
                              hipStream_t stream) {
    (void)in_sizes; (void)n_in; (void)out_size;
    const float* x = (const float*)d_in[0];
    const float* Wq = (const float*)d_in[1];
    const float* Wk = (const float*)d_in[2];
    const float* Wv = (const float*)d_in[3];
    float* out = (float*)d_out;

    char* ws = (char*)d_ws;
    size_t off = 0;
    auto alloc = [&](size_t bytes) -> void* {
        void* p = ws + off;
        off += (bytes + 255) & ~(size_t)255;
        return p;
    };
    ushort* xb = (ushort*)alloc((size_t)B_ * S_ * D_ * 2);
    ushort* Wt = (ushort*)alloc((size_t)3 * U_ * D_ * 2);
    ushort* Qb = (ushort*)alloc((size_t)B_ * S_ * U_ * 2);
    ushort* Kb = (ushort*)alloc((size_t)B_ * S_ * U_ * 2);
    ushort* Vt = (ushort*)alloc((size_t)B_ * S_ * U_ * 2);  // [B][U][S]
    ushort* P  = (ushort*)alloc((size_t)B_ * S_ * S_ * 2);
    bool full = (ws_size - off) >= (size_t)B_ * S_ * S_ * 2 + 256;
    ushort* Sc = (ushort*)alloc(full ? (size_t)B_ * S_ * S_ * 2 : (size_t)S_ * S_ * 2);

    hipFuncSetAttribute(reinterpret_cast<const void*>(proj_kernel),
                        hipFuncAttributeMaxDynamicSharedMemorySize, 131072);
    hipFuncSetAttribute(reinterpret_cast<const void*>(scores_kernel),
                        hipFuncAttributeMaxDynamicSharedMemorySize, 131072);
    hipFuncSetAttribute(reinterpret_cast<const void*>(pv_split_kernel),
                        hipFuncAttributeMaxDynamicSharedMemorySize, 131072);
    hipFuncSetAttribute(reinterpret_cast<const void*>(pv_kernel),
                        hipFuncAttributeMaxDynamicSharedMemorySize, 131072);

    const float scale = 0.036084391824351615f;  // 1/sqrt(768), folded into Q
    prep_kernel<<<7872, 256, 0, stream>>>(x, Wq, Wk, Wv, xb, Wt);
    proj_kernel<<<288, 512, 131072, stream>>>(xb, Wt, Qb, Kb, Vt, scale);

    if (full) {
        scores_kernel<<<256, 512, 131072, stream>>>(Qb, Kb, Sc);
        softmax_kernel<<<dim3(S_, B_), 256, 0, stream>>>(Sc, P);
        // Sc (33.6 MB) is dead after softmax: reuse for the kc=1 f32 partial
        // (25.2 MB).
        float* p1 = (float*)Sc;
        pv_split_kernel<<<192, 512, 131072, stream>>>(P, Vt, out, p1);
        reduce_add_kernel<<<2048, 256, 0, stream>>>(
            (float4*)out, (const float4*)p1, B_ * S_ * U_ / 4);
    } else {
        for (int b = 0; b < B_; ++b) {
            scores_kernel<<<64, 512, 131072, stream>>>(
                Qb + (size_t)b * S_ * U_, Kb + (size_t)b * S_ * U_, Sc);
            softmax_kernel<<<dim3(S_, 1), 256, 0, stream>>>(
                Sc, P + (size_t)b * S_ * S_);
        }
        pv_kernel<<<96, 512, 131072, stream>>>(P, Vt, out);
    }
}

// Round 9
// 142.288 us; speedup vs baseline: 1.1359x; 1.0224x over previous
//
#include <hip/hip_runtime.h>
#include <stdint.h>

#define B_ 4
#define S_ 2048
#define D_ 768
#define U_ 768

typedef __bf16 bf16x8 __attribute__((ext_vector_type(8)));
typedef float f32x4 __attribute__((ext_vector_type(4)));

#define AS1 __attribute__((address_space(1)))
#define AS3 __attribute__((address_space(3)))

#define BAR() __builtin_amdgcn_s_barrier()
#define WAITV6() asm volatile("s_waitcnt vmcnt(6)" ::: "memory")
#define WAITV0() asm volatile("s_waitcnt vmcnt(0)" ::: "memory")
#define PRIO(x) __builtin_amdgcn_s_setprio(x)

__device__ __forceinline__ ushort f2bf(float f) {
    union { float f; uint32_t u; } v; v.f = f;
    uint32_t r = v.u + 0x7fffu + ((v.u >> 16) & 1u);
    return (ushort)(r >> 16);
}

__device__ __forceinline__ float bflo(uint32_t u) {
    union { uint32_t u; float f; } v; v.u = u << 16; return v.f;
}
__device__ __forceinline__ float bfhi(uint32_t u) {
    union { uint32_t u; float f; } v; v.u = u & 0xffff0000u; return v.f;
}

__device__ __forceinline__ void gload_lds16(const void* gp, void* lp) {
    // width-16 global->LDS: HW scatters to (wave-uniform lds base) + lane*16
    __builtin_amdgcn_global_load_lds((AS1 void*)gp, (AS3 void*)lp, 16, 0, 0);
}

// ============================================================================
// 256x256 pipelined GEMM (BK=64, 8 waves 2Mx4N, counted vmcnt(6), XOR-swizzled
// LDS, setprio).  C = A[M,K] @ Bt[N,K]^T.
// PHASES=8: proven 4-compute-phase/tile schedule (10 barriers incl. loop pair).
// PHASES=2: merged 2-compute-phase/tile (6 barriers, 32-MFMA clusters).
//   Same load set, same issue order, same vmcnt counts, same MFMA operand
//   order => bit-identical results; only barrier placement differs.
//   WAR: every LDS region is read-issued, lgkm-consumed, then >=2 barriers
//   before the overwriting DMA issue (verified for both variants).
// MODE 0: bf16 row-major out (value*scale).  MODE 1: bf16 scatter to
// Vt[B][U][S] (ushort4-packed).  MODE 2: f32 * scale.
// LDS: sA[2][256*64] + sB[2][256*64] bf16 = 128 KiB dynamic.
// ============================================================================
template <int MODE, int PHASES>
__device__ __forceinline__ void gemm256(
    ushort* sm,
    const ushort* __restrict__ Ag, int lda,
    const ushort* __restrict__ Btg, int ldb,
    void* __restrict__ Cp, int ldc, int Kd, float scale,
    int ty, int tx)
{
    constexpr int ABUF = 256 * 64;
    ushort* sA = sm;
    ushort* sB = sm + 2 * ABUF;

    const int tid = threadIdx.x;
    const int l = tid & 63, w = tid >> 6;
    const int lr = l & 15, lg = l >> 4;
    const int wm = w >> 2, wn = w & 3;
    const int M0 = ty * 256, N0 = tx * 256;

    f32x4 acc[8][4];
#pragma unroll
    for (int m = 0; m < 8; ++m)
#pragma unroll
        for (int n = 0; n < 4; ++n)
            acc[m][n] = (f32x4){0.f, 0.f, 0.f, 0.f};

    const int NT = Kd >> 6;

    auto STA = [&](int buf, int qp, int kt) {
#pragma unroll
        for (int j = 0; j < 2; ++j) {
            int q = qp + j;
            int r0 = (w < 4) ? (q * 32 + w * 8) : (128 + q * 32 + (w - 4) * 8);
            int r = r0 + (l >> 3);
            int lc = ((l & 7) * 16) ^ ((r & 7) << 4);
            gload_lds16(Ag + (size_t)(M0 + r) * lda + kt * 64 + (lc >> 1),
                        sA + buf * ABUF + r0 * 64);
        }
    };
    auto STB = [&](int buf, int h, int kt) {
#pragma unroll
        for (int j = 0; j < 2; ++j) {
            int r0 = h * 128 + j * 64 + w * 8;
            int r = r0 + (l >> 3);
            int lc = ((l & 7) * 16) ^ ((r & 7) << 4);
            gload_lds16(Btg + (size_t)(N0 + r) * ldb + kt * 64 + (lc >> 1),
                        sB + buf * 16384 + r0 * 64);
        }
    };

    bf16x8 afr[2][2], af2[2][2], bfr[4][2];
    auto LDB = [&](int buf) {
#pragma unroll
        for (int nf = 0; nf < 4; ++nf)
#pragma unroll
            for (int ks = 0; ks < 2; ++ks) {
                int r = wn * 64 + nf * 16 + lr;
                int off = r * 128 + ((ks * 64 + lg * 16) ^ ((r & 7) << 4));
                bfr[nf][ks] = *(const bf16x8*)((const char*)(sB + buf * 16384) + off);
            }
    };
    auto LDA = [&](bf16x8 (*dst)[2], int buf, int q) {
#pragma unroll
        for (int j = 0; j < 2; ++j)
#pragma unroll
            for (int ks = 0; ks < 2; ++ks) {
                int r = wm * 128 + (2 * q + j) * 16 + lr;
                int off = r * 128 + ((ks * 64 + lg * 16) ^ ((r & 7) << 4));
                dst[j][ks] = *(const bf16x8*)((const char*)(sA + buf * ABUF) + off);
            }
    };

#define MMQA(Q, AFR)                                                           \
    _Pragma("unroll")                                                          \
    for (int j = 0; j < 2; ++j)                                                \
        _Pragma("unroll")                                                      \
        for (int nf = 0; nf < 4; ++nf)                                         \
            _Pragma("unroll")                                                  \
            for (int ks = 0; ks < 2; ++ks)                                     \
                acc[2 * (Q) + j][nf] = __builtin_amdgcn_mfma_f32_16x16x32_bf16(\
                    AFR[j][ks], bfr[nf][ks], acc[2 * (Q) + j][nf], 0, 0, 0);

    // prologue: tile0 fully + tile1's {B0,B1,A-q01}; keep 6 in flight.
    STA(0, 0, 0); STA(0, 2, 0); STB(0, 0, 0); STB(0, 1, 0);
    if (NT > 1) {
        STB(1, 0, 1); STB(1, 1, 1); STA(1, 0, 1);
        WAITV6();
    } else {
        WAITV0();
    }
    BAR();

    for (int t = 0; t < NT; ++t) {
        const int c = t & 1;
        if constexpr (PHASES == 8) {
            LDB(c); LDA(afr, c, 0);
            if (t + 1 < NT) STA(c ^ 1, 2, t + 1);
            BAR();
            PRIO(1); MMQA(0, afr); PRIO(0);
            BAR();
            LDA(afr, c, 1);
            if (t + 2 < NT) STB(c, 0, t + 2);
            BAR();
            PRIO(1); MMQA(1, afr); PRIO(0);
            BAR();
            LDA(afr, c, 2);
            if (t + 2 < NT) STB(c, 1, t + 2);
            BAR();
            PRIO(1); MMQA(2, afr); PRIO(0);
            BAR();
            LDA(afr, c, 3);
            if (t + 2 < NT) STA(c, 0, t + 2);
            BAR();
            PRIO(1); MMQA(3, afr); PRIO(0);
            if (t + 2 < NT) { WAITV6(); } else { WAITV0(); }
            BAR();
        } else {
            // phase A: quads 0,1
            LDB(c); LDA(afr, c, 0); LDA(af2, c, 1);
            if (t + 1 < NT) STA(c ^ 1, 2, t + 1);
            BAR();
            PRIO(1); MMQA(0, afr); MMQA(1, af2); PRIO(0);
            BAR();
            // phase B: quads 2,3
            LDA(afr, c, 2); LDA(af2, c, 3);
            if (t + 2 < NT) { STB(c, 0, t + 2); STB(c, 1, t + 2); STA(c, 0, t + 2); }
            BAR();
            PRIO(1); MMQA(2, afr); MMQA(3, af2); PRIO(0);
            if (t + 2 < NT) { WAITV6(); } else { WAITV0(); }
            BAR();
        }
    }
#undef MMQA

    // epilogue: C/D frag mapping col = lane&15, row = (lane>>4)*4 + i
#pragma unroll
    for (int mf = 0; mf < 8; ++mf) {
#pragma unroll
        for (int nf = 0; nf < 4; ++nf) {
            if constexpr (MODE == 1) {
                int r0 = M0 + wm * 128 + mf * 16 + lg * 4;
                int c = N0 + wn * 64 + nf * 16 + lr;
                int b = r0 >> 11, s = r0 & 2047;
                ushort4 o;
                o.x = f2bf(acc[mf][nf][0]);
                o.y = f2bf(acc[mf][nf][1]);
                o.z = f2bf(acc[mf][nf][2]);
                o.w = f2bf(acc[mf][nf][3]);
                *(ushort4*)&((ushort*)Cp)[((size_t)b * U_ + c) * S_ + s] = o;
            } else {
#pragma unroll
                for (int i = 0; i < 4; ++i) {
                    int r = M0 + wm * 128 + mf * 16 + lg * 4 + i;
                    int c = N0 + wn * 64 + nf * 16 + lr;
                    float v = acc[mf][nf][i];
                    if constexpr (MODE == 0) {
                        ((ushort*)Cp)[(size_t)r * ldc + c] = f2bf(v * scale);
                    } else {
                        ((float*)Cp)[(size_t)r * ldc + c] = v * scale;
                    }
                }
            }
        }
    }
}

// Merged QKV projection: 288 blocks. Q gets softmax scale folded in.
__global__ __launch_bounds__(512) void proj_kernel(
    const ushort* __restrict__ xb, const ushort* __restrict__ Wt,
    ushort* __restrict__ Qb, ushort* __restrict__ Kb,
    ushort* __restrict__ Vt, float qscale) {
    extern __shared__ ushort sm[];
    const int b0 = blockIdx.x;                      // 288 = 8 XCD x 36
    const int wg = (b0 & 7) * 36 + (b0 >> 3);
    const int ty = wg / 9, rem = wg % 9;
    const int z = rem / 3, tx = rem % 3;
    if (z == 0)
        gemm256<0, 8>(sm, xb, D_, Wt, D_, Qb, U_, D_, qscale, ty, tx);
    else if (z == 1)
        gemm256<0, 8>(sm, xb, D_, Wt + (size_t)U_ * D_, D_, Kb, U_, D_, 1.f, ty, tx);
    else
        gemm256<1, 8>(sm, xb, D_, Wt + (size_t)2 * U_ * D_, D_, Vt, 0, D_, 1.f, ty, tx);
}

// scores -> bf16 (scale folded into Q). 256 blocks. 2-PHASE VARIANT (A/B test).
__global__ __launch_bounds__(512) void scores_kernel(
    const ushort* __restrict__ Qb, const ushort* __restrict__ Kb,
    ushort* __restrict__ Sc) {
    extern __shared__ ushort sm[];
    const int nwg = gridDim.x;                       // 256 or 64, %8==0
    const int b0 = blockIdx.x;
    const int wg = (b0 & 7) * (nwg >> 3) + (b0 >> 3);
    const int tx = wg & 7, ty = (wg >> 3) & 7, z = wg >> 6;
    gemm256<0, 2>(sm, Qb + (size_t)z * S_ * U_, U_, Kb + (size_t)z * S_ * U_, U_,
                  Sc + (size_t)z * S_ * S_, S_, U_, 1.f, ty, tx);
}

// PV split-K=2: 192 blocks; both halves emit BF16 partials (p0, p1).
__global__ __launch_bounds__(512) void pv_split_kernel(
    const ushort* __restrict__ P, const ushort* __restrict__ Vt,
    ushort* __restrict__ p0, ushort* __restrict__ p1) {
    extern __shared__ ushort sm[];
    const int b0 = blockIdx.x;                      // 192 = 8 XCD x 24
    const int wg = (b0 & 7) * 24 + (b0 >> 3);
    const int zk = wg / 24, rem = wg % 24;
    const int z = zk >> 1, kc = zk & 1;
    const int ty = rem / 3, tx = rem % 3;
    ushort* dst = (kc ? p1 : p0) + (size_t)z * S_ * U_;
    gemm256<0, 8>(sm, P + (size_t)z * S_ * S_ + kc * 1024, S_,
                  Vt + (size_t)z * U_ * S_ + kc * 1024, S_,
                  dst, U_, 1024, 1.f, ty, tx);
}

// out = f32(p0) + f32(p1)  (bf16 partials -> 50.4 MB traffic)
__global__ void reduce_bf_kernel(float4* __restrict__ out,
                                 const uint4* __restrict__ p0,
                                 const uint4* __restrict__ p1, int n8) {
    int i = blockIdx.x * 256 + threadIdx.x;
    const int stride = gridDim.x * 256;
    for (; i < n8; i += stride) {
        uint4 a = p0[i], b = p1[i];
        float4 o0, o1;
        o0.x = bflo(a.x) + bflo(b.x); o0.y = bfhi(a.x) + bfhi(b.x);
        o0.z = bflo(a.y) + bflo(b.y); o0.w = bfhi(a.y) + bfhi(b.y);
        o1.x = bflo(a.z) + bflo(b.z); o1.y = bfhi(a.z) + bfhi(b.z);
        o1.z = bflo(a.w) + bflo(b.w); o1.w = bfhi(a.w) + bfhi(b.w);
        out[2 * i] = o0;
        out[2 * i + 1] = o1;
    }
}

// PV without split (fallback when ws lacks the full Sc region). 96 blocks.
__global__ __launch_bounds__(512) void pv_kernel(
    const ushort* __restrict__ P, const ushort* __restrict__ Vt,
    float* __restrict__ out) {
    extern __shared__ ushort sm[];
    const int b0 = blockIdx.x;                      // 96 = 8 XCD x 12
    const int wg = (b0 & 7) * 12 + (b0 >> 3);
    const int z = wg / 24, rem = wg % 24;
    const int ty = rem / 3, tx = rem % 3;
    gemm256<2, 8>(sm, P + (size_t)z * S_ * S_, S_, Vt + (size_t)z * U_ * S_, S_,
                  out + (size_t)z * S_ * U_, U_, S_, 1.f, ty, tx);
}

// ======================= small helper kernels ========================

// Merged input prep: blocks [0,6144) cast x -> bf16; blocks [6144,7872)
// transpose W{q,k,v} -> Wt bf16 [z][U][D]. Branch is block-uniform.
__global__ __launch_bounds__(256) void prep_kernel(
    const float* __restrict__ x,
    const float* __restrict__ Wq, const float* __restrict__ Wk,
    const float* __restrict__ Wv,
    ushort* __restrict__ xb, ushort* __restrict__ Wt) {
    __shared__ float tsh[32][33];
    const int bid = blockIdx.x, tid = threadIdx.x;
    if (bid < 6144) {
        int i = bid * 256 + tid;                    // n4 = 6144*256 exactly
        float4 v = ((const float4*)x)[i];
        ushort4 o;
        o.x = f2bf(v.x); o.y = f2bf(v.y); o.z = f2bf(v.z); o.w = f2bf(v.w);
        ((ushort4*)xb)[i] = o;
    } else {
        int b2 = bid - 6144;
        int zz = b2 / 576, rem = b2 % 576;
        int by = rem / 24, bx = rem % 24;
        const float* W = zz == 0 ? Wq : (zz == 1 ? Wk : Wv);
        int x0 = bx * 32, y0 = by * 32;
        int txx = tid & 31, tyy = tid >> 5;         // 32 x 8
        for (int i = tyy; i < 32; i += 8)
            tsh[i][txx] = W[(size_t)(y0 + i) * U_ + (x0 + txx)];
        __syncthreads();
        ushort* Wtz = Wt + (size_t)zz * U_ * D_;
        for (int i = tyy; i < 32; i += 8)
            Wtz[(size_t)(x0 + i) * D_ + (y0 + txx)] = f2bf(tsh[txx][i]);
    }
}

// Row softmax over bf16 scores -> bf16 P. One row per block.
__global__ __launch_bounds__(256) void softmax_kernel(
    const ushort* __restrict__ Sc, ushort* __restrict__ P) {
    size_t row = (size_t)blockIdx.y * gridDim.x + blockIdx.x;
    const uint4* r4 = (const uint4*)(Sc + row * S_);
    int t = threadIdx.x;
    int w = t >> 6, l = t & 63;
    uint4 a = r4[t];
    float e[8];
    e[0] = bflo(a.x); e[1] = bfhi(a.x);
    e[2] = bflo(a.y); e[3] = bfhi(a.y);
    e[4] = bflo(a.z); e[5] = bfhi(a.z);
    e[6] = bflo(a.w); e[7] = bfhi(a.w);
    float mx = fmaxf(fmaxf(fmaxf(e[0], e[1]), fmaxf(e[2], e[3])),
                     fmaxf(fmaxf(e[4], e[5]), fmaxf(e[6], e[7])));
#pragma unroll
    for (int off = 32; off; off >>= 1) mx = fmaxf(mx, __shfl_xor(mx, off));
    __shared__ float red[8];
    if (l == 0) red[w] = mx;
    __syncthreads();
    mx = fmaxf(fmaxf(red[0], red[1]), fmaxf(red[2], red[3]));
    float s = 0.f;
#pragma unroll
    for (int i = 0; i < 8; ++i) { e[i] = __expf(e[i] - mx); s += e[i]; }
#pragma unroll
    for (int off = 32; off; off >>= 1) s += __shfl_xor(s, off);
    if (l == 0) red[4 + w] = s;
    __syncthreads();
    float inv = 1.f / (red[4] + red[5] + red[6] + red[7]);
    uint4 o;
    o.x = (uint32_t)f2bf(e[0] * inv) | ((uint32_t)f2bf(e[1] * inv) << 16);
    o.y = (uint32_t)f2bf(e[2] * inv) | ((uint32_t)f2bf(e[3] * inv) << 16);
    o.z = (uint32_t)f2bf(e[4] * inv) | ((uint32_t)f2bf(e[5] * inv) << 16);
    o.w = (uint32_t)f2bf(e[6] * inv) | ((uint32_t)f2bf(e[7] * inv) << 16);
    ((uint4*)(P + row * S_))[t] = o;
}

extern "C" void kernel_launch(void* const* d_in, const int* in_sizes, int n_in,
                              void* d_out, int out_size, void* d_ws, size_t ws_size,
                              hipStream_t stream) {
    (void)in_sizes; (void)n_in; (void)out_size;
    const float* x = (const float*)d_in[0];
    const float* Wq = (const float*)d_in[1];
    const float* Wk = (const float*)d_in[2];
    const float* Wv = (const float*)d_in[3];
    float* out = (float*)d_out;

    char* ws = (char*)d_ws;
    size_t off = 0;
    auto alloc = [&](size_t bytes) -> void* {
        void* p = ws + off;
        off += (bytes + 255) & ~(size_t)255;
        return p;
    };
    ushort* xb = (ushort*)alloc((size_t)B_ * S_ * D_ * 2);
    ushort* Wt = (ushort*)alloc((size_t)3 * U_ * D_ * 2);
    ushort* Qb = (ushort*)alloc((size_t)B_ * S_ * U_ * 2);
    ushort* Kb = (ushort*)alloc((size_t)B_ * S_ * U_ * 2);
    ushort* Vt = (ushort*)alloc((size_t)B_ * S_ * U_ * 2);  // [B][U][S]
    ushort* P  = (ushort*)alloc((size_t)B_ * S_ * S_ * 2);
    bool full = (ws_size - off) >= (size_t)B_ * S_ * S_ * 2 + 256;
    ushort* Sc = (ushort*)alloc(full ? (size_t)B_ * S_ * S_ * 2 : (size_t)S_ * S_ * 2);

    hipFuncSetAttribute(reinterpret_cast<const void*>(proj_kernel),
                        hipFuncAttributeMaxDynamicSharedMemorySize, 131072);
    hipFuncSetAttribute(reinterpret_cast<const void*>(scores_kernel),
                        hipFuncAttributeMaxDynamicSharedMemorySize, 131072);
    hipFuncSetAttribute(reinterpret_cast<const void*>(pv_split_kernel),
                        hipFuncAttributeMaxDynamicSharedMemorySize, 131072);
    hipFuncSetAttribute(reinterpret_cast<const void*>(pv_kernel),
                        hipFuncAttributeMaxDynamicSharedMemorySize, 131072);

    const float scale = 0.036084391824351615f;  // 1/sqrt(768), folded into Q
    prep_kernel<<<7872, 256, 0, stream>>>(x, Wq, Wk, Wv, xb, Wt);
    proj_kernel<<<288, 512, 131072, stream>>>(xb, Wt, Qb, Kb, Vt, scale);

    if (full) {
        scores_kernel<<<256, 512, 131072, stream>>>(Qb, Kb, Sc);
        softmax_kernel<<<dim3(S_, B_), 256, 0, stream>>>(Sc, P);
        // Sc (33.6 MB) is dead after softmax: reuse for the two bf16 partials
        // (2 x 12.6 MB).
        ushort* p0 = Sc;
        ushort* p1 = Sc + (size_t)B_ * S_ * U_;
        pv_split_kernel<<<192, 512, 131072, stream>>>(P, Vt, p0, p1);
        reduce_bf_kernel<<<1536, 256, 0, stream>>>(
            (float4*)out, (const uint4*)p0, (const uint4*)p1, B_ * S_ * U_ / 8);
    } else {
        for (int b = 0; b < B_; ++b) {
            scores_kernel<<<64, 512, 131072, stream>>>(
                Qb + (size_t)b * S_ * U_, Kb + (size_t)b * S_ * U_, Sc);
            softmax_kernel<<<dim3(S_, 1), 256, 0, stream>>>(
                Sc, P + (size_t)b * S_ * S_);
        }
        pv_kernel<<<96, 512, 131072, stream>>>(P, Vt, out);
    }
}

// Round 10
// 135.624 us; speedup vs baseline: 1.1918x; 1.0491x over previous
//
#include <hip/hip_runtime.h>
#include <stdint.h>

#define B_ 4
#define S_ 2048
#define D_ 768
#define U_ 768

typedef __bf16 bf16x8 __attribute__((ext_vector_type(8)));
typedef float f32x4 __attribute__((ext_vector_type(4)));

#define AS1 __attribute__((address_space(1)))
#define AS3 __attribute__((address_space(3)))

#define BAR() __builtin_amdgcn_s_barrier()
#define WAITV6() asm volatile("s_waitcnt vmcnt(6)" ::: "memory")
#define WAITV0() asm volatile("s_waitcnt vmcnt(0)" ::: "memory")
#define PRIO(x) __builtin_amdgcn_s_setprio(x)

__device__ __forceinline__ ushort f2bf(float f) {
    union { float f; uint32_t u; } v; v.f = f;
    uint32_t r = v.u + 0x7fffu + ((v.u >> 16) & 1u);
    return (ushort)(r >> 16);
}

__device__ __forceinline__ float bflo(uint32_t u) {
    union { uint32_t u; float f; } v; v.u = u << 16; return v.f;
}
__device__ __forceinline__ float bfhi(uint32_t u) {
    union { uint32_t u; float f; } v; v.u = u & 0xffff0000u; return v.f;
}

__device__ __forceinline__ void gload_lds16(const void* gp, void* lp) {
    // width-16 global->LDS: HW scatters to (wave-uniform lds base) + lane*16
    __builtin_amdgcn_global_load_lds((AS1 void*)gp, (AS3 void*)lp, 16, 0, 0);
}

// ============================================================================
// 256x256 8-phase pipelined GEMM (BK=64, 8 waves 2Mx4N, counted vmcnt(6),
// XOR-swizzled LDS — conflicts measured 0, setprio around MFMA).
// C = A[M,K] @ Bt[N,K]^T.
// MODE 0: bf16 row-major out (value*scale).
// MODE 1: bf16 -> Vt[B][U][S] via LDS-transposed COALESCED stores (sm reused
//         post-loop as a [256 col][129 dword] transpose buffer; 132096 B).
// MODE 2: f32 * scale.
// GEMM LDS: sA[2][256*64] + sB[2][256*64] bf16 = 128 KiB dynamic.
// ============================================================================
template <int MODE>
__device__ __forceinline__ void gemm256(
    ushort* sm,
    const ushort* __restrict__ Ag, int lda,
    const ushort* __restrict__ Btg, int ldb,
    void* __restrict__ Cp, int ldc, int Kd, float scale,
    int ty, int tx)
{
    constexpr int ABUF = 256 * 64;
    ushort* sA = sm;
    ushort* sB = sm + 2 * ABUF;

    const int tid = threadIdx.x;
    const int l = tid & 63, w = tid >> 6;
    const int lr = l & 15, lg = l >> 4;
    const int wm = w >> 2, wn = w & 3;
    const int M0 = ty * 256, N0 = tx * 256;

    f32x4 acc[8][4];
#pragma unroll
    for (int m = 0; m < 8; ++m)
#pragma unroll
        for (int n = 0; n < 4; ++n)
            acc[m][n] = (f32x4){0.f, 0.f, 0.f, 0.f};

    const int NT = Kd >> 6;

    auto STA = [&](int buf, int qp, int kt) {
#pragma unroll
        for (int j = 0; j < 2; ++j) {
            int q = qp + j;
            int r0 = (w < 4) ? (q * 32 + w * 8) : (128 + q * 32 + (w - 4) * 8);
            int r = r0 + (l >> 3);
            int lc = ((l & 7) * 16) ^ ((r & 7) << 4);
            gload_lds16(Ag + (size_t)(M0 + r) * lda + kt * 64 + (lc >> 1),
                        sA + buf * ABUF + r0 * 64);
        }
    };
    auto STB = [&](int buf, int h, int kt) {
#pragma unroll
        for (int j = 0; j < 2; ++j) {
            int r0 = h * 128 + j * 64 + w * 8;
            int r = r0 + (l >> 3);
            int lc = ((l & 7) * 16) ^ ((r & 7) << 4);
            gload_lds16(Btg + (size_t)(N0 + r) * ldb + kt * 64 + (lc >> 1),
                        sB + buf * 16384 + r0 * 64);
        }
    };

    bf16x8 afr[2][2], bfr[4][2];
    auto LDB = [&](int buf) {
#pragma unroll
        for (int nf = 0; nf < 4; ++nf)
#pragma unroll
            for (int ks = 0; ks < 2; ++ks) {
                int r = wn * 64 + nf * 16 + lr;
                int off = r * 128 + ((ks * 64 + lg * 16) ^ ((r & 7) << 4));
                bfr[nf][ks] = *(const bf16x8*)((const char*)(sB + buf * 16384) + off);
            }
    };
    auto LDA = [&](int buf, int q) {
#pragma unroll
        for (int j = 0; j < 2; ++j)
#pragma unroll
            for (int ks = 0; ks < 2; ++ks) {
                int r = wm * 128 + (2 * q + j) * 16 + lr;
                int off = r * 128 + ((ks * 64 + lg * 16) ^ ((r & 7) << 4));
                afr[j][ks] = *(const bf16x8*)((const char*)(sA + buf * ABUF) + off);
            }
    };

#define MMQ(Q)                                                                 \
    PRIO(1);                                                                   \
    _Pragma("unroll")                                                          \
    for (int j = 0; j < 2; ++j)                                                \
        _Pragma("unroll")                                                      \
        for (int nf = 0; nf < 4; ++nf)                                         \
            _Pragma("unroll")                                                  \
            for (int ks = 0; ks < 2; ++ks)                                     \
                acc[2 * (Q) + j][nf] = __builtin_amdgcn_mfma_f32_16x16x32_bf16(\
                    afr[j][ks], bfr[nf][ks], acc[2 * (Q) + j][nf], 0, 0, 0);   \
    PRIO(0);

    STA(0, 0, 0); STA(0, 2, 0); STB(0, 0, 0); STB(0, 1, 0);
    if (NT > 1) {
        STB(1, 0, 1); STB(1, 1, 1); STA(1, 0, 1);
        WAITV6();
    } else {
        WAITV0();
    }
    BAR();

    for (int t = 0; t < NT; ++t) {
        const int c = t & 1;
        LDB(c); LDA(c, 0);
        if (t + 1 < NT) STA(c ^ 1, 2, t + 1);
        BAR();
        MMQ(0);
        BAR();
        LDA(c, 1);
        if (t + 2 < NT) STB(c, 0, t + 2);
        BAR();
        MMQ(1);
        BAR();
        LDA(c, 2);
        if (t + 2 < NT) STB(c, 1, t + 2);
        BAR();
        MMQ(2);
        BAR();
        LDA(c, 3);
        if (t + 2 < NT) STA(c, 0, t + 2);
        BAR();
        MMQ(3);
        if (t + 2 < NT) { WAITV6(); } else { WAITV0(); }
        BAR();
    }
#undef MMQ

    if constexpr (MODE == 1) {
        // ---- LDS-transposed Vt epilogue (coalesced stores) ----
        // sm reused as [256 col][129 dword] buffer (stride 129 => bank rotate).
        __syncthreads();               // all GEMM LDS reads complete
        uint32_t* smw = (uint32_t*)sm;
#pragma unroll
        for (int mf = 0; mf < 8; ++mf) {
#pragma unroll
            for (int nf = 0; nf < 4; ++nf) {
                int cc = wn * 64 + nf * 16 + lr;          // local col (u)
                int r0 = wm * 128 + mf * 16 + lg * 4;     // local row, mult 4
                uint32_t d0 = (uint32_t)f2bf(acc[mf][nf][0]) |
                              ((uint32_t)f2bf(acc[mf][nf][1]) << 16);
                uint32_t d1 = (uint32_t)f2bf(acc[mf][nf][2]) |
                              ((uint32_t)f2bf(acc[mf][nf][3]) << 16);
                smw[cc * 129 + (r0 >> 1)] = d0;
                smw[cc * 129 + (r0 >> 1) + 1] = d1;
            }
        }
        __syncthreads();
        // read row-linear, store contiguous: lane covers consecutive s.
        const int bb = M0 >> 11;                          // batch (no straddle)
        const int s0 = M0 & 2047;
        const int kd = tid & 127;                         // dword within row
        int u = tid >> 7;                                 // 0..3 start row
#pragma unroll
        for (int it = 0; it < 64; ++it) {
            uint32_t d = smw[u * 129 + kd];
            uint32_t* vrow = (uint32_t*)((ushort*)Cp +
                ((size_t)(bb * U_ + N0 + u)) * S_ + s0);
            vrow[kd] = d;
            u += 4;
        }
        return;
    }

    // epilogue: C/D frag mapping col = lane&15, row = (lane>>4)*4 + i
#pragma unroll
    for (int mf = 0; mf < 8; ++mf) {
#pragma unroll
        for (int nf = 0; nf < 4; ++nf) {
#pragma unroll
            for (int i = 0; i < 4; ++i) {
                int r = M0 + wm * 128 + mf * 16 + lg * 4 + i;
                int c = N0 + wn * 64 + nf * 16 + lr;
                float v = acc[mf][nf][i];
                if constexpr (MODE == 0) {
                    ((ushort*)Cp)[(size_t)r * ldc + c] = f2bf(v * scale);
                } else {
                    ((float*)Cp)[(size_t)r * ldc + c] = v * scale;
                }
            }
        }
    }
}

// Merged QKV projection: 288 blocks = 2 dispatch rounds. z=2 (Vt, heavier
// epilogue) blocks are ordered FIRST within each XCD chunk so round 2
// (last 32 blocks) contains only light Q/K blocks.
__global__ __launch_bounds__(512) void proj_kernel(
    const ushort* __restrict__ xb, const ushort* __restrict__ Wt,
    ushort* __restrict__ Qb, ushort* __restrict__ Kb,
    ushort* __restrict__ Vt, float qscale) {
    extern __shared__ ushort sm[];
    const int b0 = blockIdx.x;                      // 288 = 8 XCD x 36
    const int i = b0 & 7, j = b0 >> 3;              // XCD chunk, order in chunk
    int z, ty, tx;
    if (j < 12) {                                   // dispatched first: V
        z = 2; ty = i * 4 + j / 3; tx = j % 3;
    } else {
        int j2 = j - 12;
        z = j2 / 12;                                // 0 then 1
        int j3 = j2 % 12;
        ty = i * 4 + j3 / 3; tx = j3 % 3;
    }
    if (z == 0)
        gemm256<0>(sm, xb, D_, Wt, D_, Qb, U_, D_, qscale, ty, tx);
    else if (z == 1)
        gemm256<0>(sm, xb, D_, Wt + (size_t)U_ * D_, D_, Kb, U_, D_, 1.f, ty, tx);
    else
        gemm256<1>(sm, xb, D_, Wt + (size_t)2 * U_ * D_, D_, Vt, 0, D_, 1.f, ty, tx);
}

// scores -> bf16 (scale folded into Q). 256 blocks. 8-phase (reverted).
__global__ __launch_bounds__(512) void scores_kernel(
    const ushort* __restrict__ Qb, const ushort* __restrict__ Kb,
    ushort* __restrict__ Sc) {
    extern __shared__ ushort sm[];
    const int nwg = gridDim.x;                       // 256 or 64, %8==0
    const int b0 = blockIdx.x;
    const int wg = (b0 & 7) * (nwg >> 3) + (b0 >> 3);
    const int tx = wg & 7, ty = (wg >> 3) & 7, z = wg >> 6;
    gemm256<0>(sm, Qb + (size_t)z * S_ * U_, U_, Kb + (size_t)z * S_ * U_, U_,
               Sc + (size_t)z * S_ * S_, S_, U_, 1.f, ty, tx);
}

// PV split-K=2: 192 blocks; both halves emit BF16 partials (p0, p1).
__global__ __launch_bounds__(512) void pv_split_kernel(
    const ushort* __restrict__ P, const ushort* __restrict__ Vt,
    ushort* __restrict__ p0, ushort* __restrict__ p1) {
    extern __shared__ ushort sm[];
    const int b0 = blockIdx.x;                      // 192 = 8 XCD x 24
    const int wg = (b0 & 7) * 24 + (b0 >> 3);
    const int zk = wg / 24, rem = wg % 24;
    const int z = zk >> 1, kc = zk & 1;
    const int ty = rem / 3, tx = rem % 3;
    ushort* dst = (kc ? p1 : p0) + (size_t)z * S_ * U_;
    gemm256<0>(sm, P + (size_t)z * S_ * S_ + kc * 1024, S_,
               Vt + (size_t)z * U_ * S_ + kc * 1024, S_,
               dst, U_, 1024, 1.f, ty, tx);
}

// out = f32(p0) + f32(p1)  (bf16 partials -> 50.4 MB traffic)
__global__ void reduce_bf_kernel(float4* __restrict__ out,
                                 const uint4* __restrict__ p0,
                                 const uint4* __restrict__ p1, int n8) {
    int i = blockIdx.x * 256 + threadIdx.x;
    const int stride = gridDim.x * 256;
    for (; i < n8; i += stride) {
        uint4 a = p0[i], b = p1[i];
        float4 o0, o1;
        o0.x = bflo(a.x) + bflo(b.x); o0.y = bfhi(a.x) + bfhi(b.x);
        o0.z = bflo(a.y) + bflo(b.y); o0.w = bfhi(a.y) + bfhi(b.y);
        o1.x = bflo(a.z) + bflo(b.z); o1.y = bfhi(a.z) + bfhi(b.z);
        o1.z = bflo(a.w) + bflo(b.w); o1.w = bfhi(a.w) + bfhi(b.w);
        out[2 * i] = o0;
        out[2 * i + 1] = o1;
    }
}

// PV without split (fallback when ws lacks the full Sc region). 96 blocks.
__global__ __launch_bounds__(512) void pv_kernel(
    const ushort* __restrict__ P, const ushort* __restrict__ Vt,
    float* __restrict__ out) {
    extern __shared__ ushort sm[];
    const int b0 = blockIdx.x;                      // 96 = 8 XCD x 12
    const int wg = (b0 & 7) * 12 + (b0 >> 3);
    const int z = wg / 24, rem = wg % 24;
    const int ty = rem / 3, tx = rem % 3;
    gemm256<2>(sm, P + (size_t)z * S_ * S_, S_, Vt + (size_t)z * U_ * S_, S_,
               out + (size_t)z * S_ * U_, U_, S_, 1.f, ty, tx);
}

// ======================= small helper kernels ========================

// Merged input prep: blocks [0,6144) cast x -> bf16; blocks [6144,7872)
// transpose W{q,k,v} -> Wt bf16 [z][U][D]. Branch is block-uniform.
__global__ __launch_bounds__(256) void prep_kernel(
    const float* __restrict__ x,
    const float* __restrict__ Wq, const float* __restrict__ Wk,
    const float* __restrict__ Wv,
    ushort* __restrict__ xb, ushort* __restrict__ Wt) {
    __shared__ float tsh[32][33];
    const int bid = blockIdx.x, tid = threadIdx.x;
    if (bid < 6144) {
        int i = bid * 256 + tid;                    // n4 = 6144*256 exactly
        float4 v = ((const float4*)x)[i];
        ushort4 o;
        o.x = f2bf(v.x); o.y = f2bf(v.y); o.z = f2bf(v.z); o.w = f2bf(v.w);
        ((ushort4*)xb)[i] = o;
    } else {
        int b2 = bid - 6144;
        int zz = b2 / 576, rem = b2 % 576;
        int by = rem / 24, bx = rem % 24;
        const float* W = zz == 0 ? Wq : (zz == 1 ? Wk : Wv);
        int x0 = bx * 32, y0 = by * 32;
        int txx = tid & 31, tyy = tid >> 5;         // 32 x 8
        for (int i = tyy; i < 32; i += 8)
            tsh[i][txx] = W[(size_t)(y0 + i) * U_ + (x0 + txx)];
        __syncthreads();
        ushort* Wtz = Wt + (size_t)zz * U_ * D_;
        for (int i = tyy; i < 32; i += 8)
            Wtz[(size_t)(x0 + i) * D_ + (y0 + txx)] = f2bf(tsh[txx][i]);
    }
}

// Row softmax over bf16 scores -> bf16 P. One row per block.
__global__ __launch_bounds__(256) void softmax_kernel(
    const ushort* __restrict__ Sc, ushort* __restrict__ P) {
    size_t row = (size_t)blockIdx.y * gridDim.x + blockIdx.x;
    const uint4* r4 = (const uint4*)(Sc + row * S_);
    int t = threadIdx.x;
    int w = t >> 6, l = t & 63;
    uint4 a = r4[t];
    float e[8];
    e[0] = bflo(a.x); e[1] = bfhi(a.x);
    e[2] = bflo(a.y); e[3] = bfhi(a.y);
    e[4] = bflo(a.z); e[5] = bfhi(a.z);
    e[6] = bflo(a.w); e[7] = bfhi(a.w);
    float mx = fmaxf(fmaxf(fmaxf(e[0], e[1]), fmaxf(e[2], e[3])),
                     fmaxf(fmaxf(e[4], e[5]), fmaxf(e[6], e[7])));
#pragma unroll
    for (int off = 32; off; off >>= 1) mx = fmaxf(mx, __shfl_xor(mx, off));
    __shared__ float red[8];
    if (l == 0) red[w] = mx;
    __syncthreads();
    mx = fmaxf(fmaxf(red[0], red[1]), fmaxf(red[2], red[3]));
    float s = 0.f;
#pragma unroll
    for (int i = 0; i < 8; ++i) { e[i] = __expf(e[i] - mx); s += e[i]; }
#pragma unroll
    for (int off = 32; off; off >>= 1) s += __shfl_xor(s, off);
    if (l == 0) red[4 + w] = s;
    __syncthreads();
    float inv = 1.f / (red[4] + red[5] + red[6] + red[7]);
    uint4 o;
    o.x = (uint32_t)f2bf(e[0] * inv) | ((uint32_t)f2bf(e[1] * inv) << 16);
    o.y = (uint32_t)f2bf(e[2] * inv) | ((uint32_t)f2bf(e[3] * inv) << 16);
    o.z = (uint32_t)f2bf(e[4] * inv) | ((uint32_t)f2bf(e[5] * inv) << 16);
    o.w = (uint32_t)f2bf(e[6] * inv) | ((uint32_t)f2bf(e[7] * inv) << 16);
    ((uint4*)(P + row * S_))[t] = o;
}

extern "C" void kernel_launch(void* const* d_in, const int* in_sizes, int n_in,
                              void* d_out, int out_size, void* d_ws, size_t ws_size,
                              hipStream_t stream) {
    (void)in_sizes; (void)n_in; (void)out_size;
    const float* x = (const float*)d_in[0];
    const float* Wq = (const float*)d_in[1];
    const float* Wk = (const float*)d_in[2];
    const float* Wv = (const float*)d_in[3];
    float* out = (float*)d_out;

    char* ws = (char*)d_ws;
    size_t off = 0;
    auto alloc = [&](size_t bytes) -> void* {
        void* p = ws + off;
        off += (bytes + 255) & ~(size_t)255;
        return p;
    };
    ushort* xb = (ushort*)alloc((size_t)B_ * S_ * D_ * 2);
    ushort* Wt = (ushort*)alloc((size_t)3 * U_ * D_ * 2);
    ushort* Qb = (ushort*)alloc((size_t)B_ * S_ * U_ * 2);
    ushort* Kb = (ushort*)alloc((size_t)B_ * S_ * U_ * 2);
    ushort* Vt = (ushort*)alloc((size_t)B_ * S_ * U_ * 2);  // [B][U][S]
    ushort* P  = (ushort*)alloc((size_t)B_ * S_ * S_ * 2);
    bool full = (ws_size - off) >= (size_t)B_ * S_ * S_ * 2 + 256;
    ushort* Sc = (ushort*)alloc(full ? (size_t)B_ * S_ * S_ * 2 : (size_t)S_ * S_ * 2);

    hipFuncSetAttribute(reinterpret_cast<const void*>(proj_kernel),
                        hipFuncAttributeMaxDynamicSharedMemorySize, 135168);
    hipFuncSetAttribute(reinterpret_cast<const void*>(scores_kernel),
                        hipFuncAttributeMaxDynamicSharedMemorySize, 131072);
    hipFuncSetAttribute(reinterpret_cast<const void*>(pv_split_kernel),
                        hipFuncAttributeMaxDynamicSharedMemorySize, 131072);
    hipFuncSetAttribute(reinterpret_cast<const void*>(pv_kernel),
                        hipFuncAttributeMaxDynamicSharedMemorySize, 131072);

    const float scale = 0.036084391824351615f;  // 1/sqrt(768), folded into Q
    prep_kernel<<<7872, 256, 0, stream>>>(x, Wq, Wk, Wv, xb, Wt);
    // 132096 B dynamic LDS: max(GEMM 131072, transpose 256*129*4)
    proj_kernel<<<288, 512, 132096, stream>>>(xb, Wt, Qb, Kb, Vt, scale);

    if (full) {
        scores_kernel<<<256, 512, 131072, stream>>>(Qb, Kb, Sc);
        softmax_kernel<<<dim3(S_, B_), 256, 0, stream>>>(Sc, P);
        // Sc (33.6 MB) is dead after softmax: reuse for the two bf16 partials
        // (2 x 12.6 MB).
        ushort* p0 = Sc;
        ushort* p1 = Sc + (size_t)B_ * S_ * U_;
        pv_split_kernel<<<192, 512, 131072, stream>>>(P, Vt, p0, p1);
        reduce_bf_kernel<<<1536, 256, 0, stream>>>(
            (float4*)out, (const uint4*)p0, (const uint4*)p1, B_ * S_ * U_ / 8);
    } else {
        for (int b = 0; b < B_; ++b) {
            scores_kernel<<<64, 512, 131072, stream>>>(
                Qb + (size_t)b * S_ * U_, Kb + (size_t)b * S_ * U_, Sc);
            softmax_kernel<<<dim3(S_, 1), 256, 0, stream>>>(
                Sc, P + (size_t)b * S_ * S_);
        }
        pv_kernel<<<96, 512, 131072, stream>>>(P, Vt, out);
    }
}